// Round 1
// baseline (3182.251 us; speedup 1.0000x reference)
//
#include <hip/hip_runtime.h>
#include <cstdint>

// Problem constants (from reference)
#define N_NODES 50000
#define FEAT    128
#define HID     64
#define NREL    3
#define NTREE   2
#define NEDGE   500000
#define NCLS    2

__device__ __forceinline__ float wave_red(float v){
  #pragma unroll
  for(int off = 32; off > 0; off >>= 1) v += __shfl_xor(v, off, 64);
  return v;
}

// ---------------- CSR build ----------------
__global__ void k_hist(const int* __restrict__ dst, int E, int* __restrict__ counts){
  int e = blockIdx.x * 256 + threadIdx.x;
  if(e < E) atomicAdd(&counts[dst[e]], 1);
}

__global__ void k_scan1(const int* __restrict__ counts, int n,
                        int* __restrict__ indptr, int* __restrict__ blksum){
  __shared__ int s[512];
  int tid = threadIdx.x;
  int i = blockIdx.x * 512 + tid;
  int v = (i < n) ? counts[i] : 0;
  s[tid] = v; __syncthreads();
  for(int off = 1; off < 512; off <<= 1){
    int t = (tid >= off) ? s[tid - off] : 0;
    __syncthreads();
    s[tid] += t;
    __syncthreads();
  }
  if(i < n) indptr[i + 1] = s[tid];
  if(tid == 511) blksum[blockIdx.x] = s[511];
}

__global__ void k_scan2(int* blksum, int nb){
  if(threadIdx.x == 0 && blockIdx.x == 0){
    int acc = 0;
    for(int b = 0; b < nb; b++){ int t = blksum[b]; blksum[b] = acc; acc += t; }
  }
}

__global__ void k_scan3(int* __restrict__ indptr, const int* __restrict__ blkoff, int n){
  int i = blockIdx.x * 256 + threadIdx.x;
  if(i == 0) indptr[0] = 0;
  if(i < n) indptr[i + 1] += blkoff[i >> 9];
}

__global__ void k_fill(const int* __restrict__ src, const int* __restrict__ dst, int E,
                       const int* __restrict__ indptr, int* __restrict__ cursor,
                       int* __restrict__ csr_src, int* __restrict__ csr_eid){
  int e = blockIdx.x * 256 + threadIdx.x;
  if(e < E){
    int d = dst[e];
    int p = indptr[d] + atomicAdd(&cursor[d], 1);
    csr_src[p] = src[e];
    csr_eid[p] = e;
  }
}

// ---------------- mean aggregation via CSR (gather, no fp atomics) ----------------
template<int F>
__global__ void k_agg_mean(const float* __restrict__ x, const int* __restrict__ indptr,
                           const int* __restrict__ csr_src, float* __restrict__ out){
  int lane = threadIdx.x & 63, wid = threadIdx.x >> 6;
  int node = blockIdx.x * 4 + wid;
  if(node >= N_NODES) return;
  int beg = indptr[node], end = indptr[node + 1];
  int cnt = end - beg;
  float sc = 1.0f / (float)(cnt >= 1 ? cnt : 1);
  if(F == 128){
    const float2* x2 = (const float2*)x;
    float ax = 0.f, ay = 0.f;
    for(int j = beg; j < end; j++){
      float2 v = x2[(size_t)csr_src[j] * 64 + lane];
      ax += v.x; ay += v.y;
    }
    float2 o; o.x = ax * sc; o.y = ay * sc;
    ((float2*)out)[(size_t)node * 64 + lane] = o;
  } else {
    float a = 0.f;
    for(int j = beg; j < end; j++) a += x[(size_t)csr_src[j] * 64 + lane];
    out[(size_t)node * 64 + lane] = a * sc;
  }
}

// ---------------- generic fused node GEMM: out = EPI(X1@W1 + X2@W2 + b) ----------------
// EPI: 0 = none, 1 = relu, 2 = multiply by xmul elementwise
template<int HOUT, int EPI>
__global__ void k_gemm(const float* __restrict__ X1, int K1, const float* __restrict__ W1,
                       const float* __restrict__ X2, int K2, const float* __restrict__ W2,
                       const float* __restrict__ bias, const float* __restrict__ xmul,
                       float* __restrict__ out){
  constexpr int NB = (HOUT == 64) ? 16 : 8;
  __shared__ float xs[NB][256];
  int tid = threadIdx.x;
  int node0 = blockIdx.x * NB;
  int Kt = K1 + K2;
  int nf4 = Kt >> 2, K14 = K1 >> 2, K24 = K2 >> 2;
  const float4* X14 = (const float4*)X1;
  const float4* X24 = (const float4*)X2;
  for(int t = tid; t < NB * nf4; t += 256){
    int nd = t / nf4, q = t - nd * nf4;
    float4 v;
    if(q < K14) v = X14[(size_t)(node0 + nd) * K14 + q];
    else        v = X24[(size_t)(node0 + nd) * K24 + (q - K14)];
    *(float4*)&xs[nd][q * 4] = v;
  }
  __syncthreads();
  int col = tid % HOUT, grp = tid / HOUT;
  int nb_base = grp * 4;
  float acc0 = 0.f, acc1 = 0.f, acc2 = 0.f, acc3 = 0.f;
  for(int k = 0; k < K1; k++){
    float w = W1[k * HOUT + col];
    acc0 += xs[nb_base + 0][k] * w;
    acc1 += xs[nb_base + 1][k] * w;
    acc2 += xs[nb_base + 2][k] * w;
    acc3 += xs[nb_base + 3][k] * w;
  }
  for(int k = 0; k < K2; k++){
    float w = W2[k * HOUT + col];
    acc0 += xs[nb_base + 0][K1 + k] * w;
    acc1 += xs[nb_base + 1][K1 + k] * w;
    acc2 += xs[nb_base + 2][K1 + k] * w;
    acc3 += xs[nb_base + 3][K1 + k] * w;
  }
  float bv = bias ? bias[col] : 0.f;
  float accs[4] = {acc0, acc1, acc2, acc3};
  #pragma unroll
  for(int i = 0; i < 4; i++){
    int node = node0 + nb_base + i;
    float r = accs[i] + bv;
    if(EPI == 1) r = fmaxf(r, 0.f);
    if(EPI == 2) r *= xmul[(size_t)node * HOUT + col];
    out[(size_t)node * HOUT + col] = r;
  }
}

// ---------------- gating + lo = y + a0*t0 + a1*t1 (in place over y) ----------------
__global__ void k_gates_lo(const float* __restrict__ t0, const float* __restrict__ t1,
                           float* __restrict__ y,
                           const float* __restrict__ gate_W, const float* __restrict__ gate_b){
  int lane = threadIdx.x & 63, wid = threadIdx.x >> 6;
  int node = blockIdx.x * 4 + wid;
  if(node >= N_NODES) return;
  size_t idx = (size_t)node * 64 + lane;
  float t0v = t0[idx], t1v = t1[idx], yv = y[idx];
  float g0 = wave_red(t0v * gate_W[lane]) + gate_b[0];
  float g1 = wave_red(t1v * gate_W[64 + lane]) + gate_b[1];
  float m = fmaxf(g0, g1);
  float e0 = expf(g0 - m), e1 = expf(g1 - m);
  float a0 = e0 / (e0 + e1);
  y[idx] = yv + a0 * t0v + (1.f - a0) * t1v;
}

// ---------------- constant-vector precomputes ----------------
__global__ void k_cvec_e(const float* __restrict__ edge_emb, const float* __restrict__ ea_W1,
                         const float* __restrict__ ea_b1, float* __restrict__ cvec){
  int j = threadIdx.x; // 128 threads
  float s = ea_b1[j];
  for(int k = 0; k < 64; k++) s += edge_emb[k] * ea_W1[(128 + k) * 128 + j];
  cvec[j] = s;
}

__global__ void k_cvec_fm(const float* __restrict__ node_emb, const float* __restrict__ fm_W,
                          const float* __restrict__ fm_b, float* __restrict__ cvec){
  int j = threadIdx.x; // 128 threads
  float s = fm_b[j];
  for(int k = 0; k < 64; k++) s += node_emb[k] * fm_W[(192 + k) * 128 + j];
  cvec[j] = s;
}

// ---------------- per-edge MLP (factored): em = relu(A[src]+B[dst]+c)·W2 + b2 ----------------
__global__ void k_em(const float* __restrict__ A, const float* __restrict__ B,
                     const int* __restrict__ src, const int* __restrict__ dst,
                     const float* __restrict__ cvec, const float* __restrict__ W2,
                     const float* __restrict__ b2, float* __restrict__ em, int E){
  int lane = threadIdx.x & 63, wid = threadIdx.x >> 6;
  int e = blockIdx.x * 4 + wid;
  if(e >= E) return;
  int s = src[e], d = dst[e];
  const float2* A2 = (const float2*)A;
  const float2* B2 = (const float2*)B;
  float2 a = A2[(size_t)s * 64 + lane];
  float2 b = B2[(size_t)d * 64 + lane];
  float2 c = ((const float2*)cvec)[lane];
  float2 w = ((const float2*)W2)[lane];
  float h0 = fmaxf(a.x + b.x + c.x, 0.f);
  float h1 = fmaxf(a.y + b.y + c.y, 0.f);
  float r = wave_red(h0 * w.x + h1 * w.y);
  if(lane == 0) em[e] = r + b2[0];
}

// ---------------- min/max reduction over em ----------------
__global__ void k_minmax_part(const float* __restrict__ em, int n,
                              float* __restrict__ pmn, float* __restrict__ pmx){
  __shared__ float smn[256], smx[256];
  int tid = threadIdx.x;
  float mn = 3.4e38f, mx = -3.4e38f;
  for(int i = blockIdx.x * 256 + tid; i < n; i += gridDim.x * 256){
    float v = em[i];
    mn = fminf(mn, v); mx = fmaxf(mx, v);
  }
  smn[tid] = mn; smx[tid] = mx; __syncthreads();
  for(int s = 128; s > 0; s >>= 1){
    if(tid < s){ smn[tid] = fminf(smn[tid], smn[tid + s]); smx[tid] = fmaxf(smx[tid], smx[tid + s]); }
    __syncthreads();
  }
  if(tid == 0){ pmn[blockIdx.x] = smn[0]; pmx[blockIdx.x] = smx[0]; }
}

__global__ void k_minmax_final(const float* __restrict__ pmn, const float* __restrict__ pmx,
                               int nb, float* __restrict__ scal){
  __shared__ float smn[256], smx[256];
  int tid = threadIdx.x;
  float mn = 3.4e38f, mx = -3.4e38f;
  if(tid < nb){ mn = pmn[tid]; mx = pmx[tid]; }
  smn[tid] = mn; smx[tid] = mx; __syncthreads();
  for(int s = 128; s > 0; s >>= 1){
    if(tid < s){ smn[tid] = fminf(smn[tid], smn[tid + s]); smx[tid] = fmaxf(smx[tid], smx[tid + s]); }
    __syncthreads();
  }
  if(tid == 0){
    scal[0] = smn[0];
    scal[1] = 1.0f / fmaxf(smx[0] - smn[0], 1e-30f);
  }
}

// ---------------- GCN degree: deg[n] = 1 + sum_j w_j ----------------
__global__ void k_deg(const int* __restrict__ indptr, const int* __restrict__ eid,
                      const float* __restrict__ em, const float* __restrict__ scal,
                      float* __restrict__ deg){
  int i = blockIdx.x * 256 + threadIdx.x;
  if(i >= N_NODES) return;
  float mn = scal[0], inv = scal[1];
  float s = 1.f;
  int beg = indptr[i], end = indptr[i + 1];
  for(int j = beg; j < end; j++) s += (em[eid[j]] - mn) * inv;
  deg[i] = s;
}

// ---------------- GCN layer (gather): out = relu?(sum norm*xW[src] + xW[n]/deg + b) ----------------
template<int RELU>
__global__ void k_gcn(const float* __restrict__ xW, const int* __restrict__ indptr,
                      const int* __restrict__ csr_src, const int* __restrict__ csr_eid,
                      const float* __restrict__ em, const float* __restrict__ scal,
                      const float* __restrict__ deg, const float* __restrict__ bias,
                      float* __restrict__ out, int ostride){
  int lane = threadIdx.x & 63, wid = threadIdx.x >> 6;
  int node = blockIdx.x * 4 + wid;
  if(node >= N_NODES) return;
  float mn = scal[0], inv = scal[1];
  float dn = deg[node];
  float dinvn = rsqrtf(dn);
  float acc = 0.f;
  int beg = indptr[node], end = indptr[node + 1];
  for(int j = beg; j < end; j++){
    int s = csr_src[j];
    int e = csr_eid[j];
    float w = (em[e] - mn) * inv;
    float nrm = dinvn * w * rsqrtf(deg[s]);
    acc += nrm * xW[(size_t)s * 64 + lane];
  }
  float r = acc + xW[(size_t)node * 64 + lane] / dn + bias[lane];
  if(RELU) r = fmaxf(r, 0.f);
  out[(size_t)node * ostride + lane] = r;
}

// ---------------- final logits + log_softmax ----------------
__global__ void k_logits(const float* __restrict__ xt, const float* __restrict__ lin_W,
                         const float* __restrict__ lin_b, float* __restrict__ out){
  int lane = threadIdx.x & 63, wid = threadIdx.x >> 6;
  int node = blockIdx.x * 4 + wid;
  if(node >= N_NODES) return;
  float a0 = 0.f, a1 = 0.f;
  #pragma unroll
  for(int q = 0; q < 3; q++){
    int k = q * 64 + lane;
    float v = xt[(size_t)node * 192 + k];
    a0 += v * lin_W[k * 2 + 0];
    a1 += v * lin_W[k * 2 + 1];
  }
  a0 = wave_red(a0);
  a1 = wave_red(a1);
  if(lane == 0){
    float l0 = fminf(fmaxf(a0 + lin_b[0], -1e10f), 1e10f);
    float l1 = fminf(fmaxf(a1 + lin_b[1], -1e10f), 1e10f);
    float m = fmaxf(l0, l1);
    float d = expf(l0 - m) + expf(l1 - m);
    float ls = m + logf(d);
    out[(size_t)node * 2 + 0] = l0 - ls;
    out[(size_t)node * 2 + 1] = l1 - ls;
  }
}

// =====================================================================
extern "C" void kernel_launch(void* const* d_in, const int* in_sizes, int n_in,
                              void* d_out, int out_size, void* d_ws, size_t ws_size,
                              hipStream_t stream){
  (void)in_sizes; (void)n_in; (void)out_size;
  const int N = N_NODES, E = NEDGE;

  const float* x        = (const float*)d_in[0];
  const int*  edge_main = (const int*)d_in[1];
  const int*  edge_tree = (const int*)d_in[2];
  const float* sage_Wl0 = (const float*)d_in[3];
  const float* sage_Wr0 = (const float*)d_in[4];
  const float* sage_b0  = (const float*)d_in[5];
  const float* sage_Wl1 = (const float*)d_in[6];
  const float* sage_Wr1 = (const float*)d_in[7];
  const float* sage_b1  = (const float*)d_in[8];
  const float* tree_Wl  = (const float*)d_in[9];
  const float* tree_Wr  = (const float*)d_in[10];
  const float* tree_b   = (const float*)d_in[11];
  const float* gate_W   = (const float*)d_in[12];
  const float* gate_b   = (const float*)d_in[13];
  const float* node_emb = (const float*)d_in[14];
  const float* edge_emb = (const float*)d_in[15];
  const float* fm_W     = (const float*)d_in[16];
  const float* fm_b     = (const float*)d_in[17];
  const float* ea_W1    = (const float*)d_in[18];
  const float* ea_b1    = (const float*)d_in[19];
  const float* ea_W2    = (const float*)d_in[20];
  const float* ea_b2    = (const float*)d_in[21];
  const float* gcn_W0   = (const float*)d_in[22];
  const float* gcn_b0   = (const float*)d_in[23];
  const float* gcn_W1   = (const float*)d_in[24];
  const float* gcn_b1   = (const float*)d_in[25];
  const float* lin_W    = (const float*)d_in[26];
  const float* lin_b    = (const float*)d_in[27];

  float* out_lsm   = (float*)d_out;              // [N,2]
  float* out_xtemp = (float*)d_out + (size_t)N * NCLS; // [N,192]

  // ---- workspace layout (~101 MB) ----
  char* ws = (char*)d_ws;
  size_t off = 0;
  auto alloc = [&](size_t bytes) -> void* {
    off = (off + 255) & ~(size_t)255;
    void* p = ws + off;
    off += bytes;
    return p;
  };
  float* P1     = (float*)alloc((size_t)N * 128 * 4); // agg / A / mx
  float* P5     = (float*)alloc((size_t)N * 128 * 4); // B
  float* P2     = (float*)alloc((size_t)N * 64 * 4);  // y0 / tree0 / xW
  float* P3     = (float*)alloc((size_t)N * 64 * 4);  // y -> lo
  float* P4     = (float*)alloc((size_t)N * 64 * 4);  // tree1 / z0
  float* P6     = (float*)alloc((size_t)E * 4);       // em
  float* degb   = (float*)alloc((size_t)N * 4);
  int*   counts = (int*)alloc((size_t)N * 4);         // also cursor
  int*   indptr_m = (int*)alloc((size_t)(N + 1) * 4);
  int*   src_m  = (int*)alloc((size_t)E * 4);
  int*   eid_m  = (int*)alloc((size_t)E * 4);
  int*   indptr_t = (int*)alloc((size_t)(N + 1) * 4);
  int*   src_t  = (int*)alloc((size_t)E * 4);
  int*   eid_t  = (int*)alloc((size_t)E * 4);
  int*   blksum = (int*)alloc(512 * 4);
  float* cvecE  = (float*)alloc(128 * 4);
  float* cvecF  = (float*)alloc(128 * 4);
  float* pmn    = (float*)alloc(256 * 4);
  float* pmx    = (float*)alloc(256 * 4);
  float* scal   = (float*)alloc(8);
  if(ws_size < off) return; // workspace too small -> fail loudly via validation

  const int GE  = (E + 255) / 256;      // edge-parallel grids
  const int GN4 = (N + 3) / 4;          // wave-per-node grids
  const int GS1 = (N + 511) / 512;      // scan chunks (= 98)
  const int GN  = (N + 255) / 256;

  auto buildCSR = [&](const int* src, const int* dst, int* indptr, int* csr_src, int* csr_eid){
    hipMemsetAsync(counts, 0, (size_t)N * 4, stream);
    k_hist<<<GE, 256, 0, stream>>>(dst, E, counts);
    k_scan1<<<GS1, 512, 0, stream>>>(counts, N, indptr, blksum);
    k_scan2<<<1, 64, 0, stream>>>(blksum, GS1);
    k_scan3<<<GN, 256, 0, stream>>>(indptr, blksum, N);
    hipMemsetAsync(counts, 0, (size_t)N * 4, stream); // cursor
    k_fill<<<GE, 256, 0, stream>>>(src, dst, E, indptr, counts, csr_src, csr_eid);
  };

  for(int r = 0; r < NREL; r++){
    const int* srcM = edge_main + (size_t)r * 2 * E;
    const int* dstM = srcM + E;

    // ---- CSR for main edges ----
    buildCSR(srcM, dstM, indptr_m, src_m, eid_m);

    // ---- SAGE layer 0: y0 = relu(agg(x)@Wl0 + x@Wr0 + b0) ----
    k_agg_mean<128><<<GN4, 256, 0, stream>>>(x, indptr_m, src_m, P1);
    k_gemm<64, 1><<<N / 16, 256, 0, stream>>>(P1, 128, sage_Wl0 + (size_t)r * 8192,
                                              x, 128, sage_Wr0 + (size_t)r * 8192,
                                              sage_b0 + r * 64, nullptr, P2);
    // ---- SAGE layer 1: y = agg(y0)@Wl1 + y0@Wr1 + b1 ----
    k_agg_mean<64><<<GN4, 256, 0, stream>>>(P2, indptr_m, src_m, P1);
    k_gemm<64, 0><<<N / 16, 256, 0, stream>>>(P1, 64, sage_Wl1 + (size_t)r * 4096,
                                              P2, 64, sage_Wr1 + (size_t)r * 4096,
                                              sage_b1 + r * 64, nullptr, P3);

    // ---- tree branches ----
    for(int t = 0; t < NTREE; t++){
      const int* srcT = edge_tree + ((size_t)(r * NTREE + t) * 2) * E;
      const int* dstT = srcT + E;
      buildCSR(srcT, dstT, indptr_t, src_t, eid_t);
      k_agg_mean<128><<<GN4, 256, 0, stream>>>(x, indptr_t, src_t, P1);
      k_gemm<64, 1><<<N / 16, 256, 0, stream>>>(P1, 128, tree_Wl + (size_t)(r * NTREE + t) * 8192,
                                                x, 128, tree_Wr + (size_t)(r * NTREE + t) * 8192,
                                                tree_b + (r * NTREE + t) * 64, nullptr,
                                                (t == 0) ? P2 : P4);
    }

    // ---- gating + lo (in place over P3) ----
    k_gates_lo<<<GN4, 256, 0, stream>>>(P2, P4, P3, gate_W + (size_t)r * 128, gate_b + r * 2);

    // ---- edge MLP, factored: A = lo@W1[0:64], B = lo@W1[64:128], c = emb@W1[128:192]+b1 ----
    k_cvec_e<<<1, 128, 0, stream>>>(edge_emb + r * 64, ea_W1, ea_b1, cvecE);
    k_gemm<128, 0><<<N / 8, 256, 0, stream>>>(P3, 64, ea_W1,
                                              nullptr, 0, nullptr, nullptr, nullptr, P1); // A
    k_gemm<128, 0><<<N / 8, 256, 0, stream>>>(P3, 64, ea_W1 + 64 * 128,
                                              nullptr, 0, nullptr, nullptr, nullptr, P5); // B
    k_em<<<(E + 3) / 4, 256, 0, stream>>>(P1, P5, srcM, dstM, cvecE, ea_W2, ea_b2, P6, E);
    k_minmax_part<<<256, 256, 0, stream>>>(P6, E, pmn, pmx);
    k_minmax_final<<<1, 256, 0, stream>>>(pmn, pmx, 256, scal);

    // ---- feature mask: mx = x * (lo@fmW[0:64] + x@fmW[64:192] + cvecF) ----
    k_cvec_fm<<<1, 128, 0, stream>>>(node_emb + r * 64, fm_W + (size_t)r * 32768,
                                     fm_b + r * 128, cvecF);
    k_gemm<128, 2><<<N / 8, 256, 0, stream>>>(P3, 64, fm_W + (size_t)r * 32768,
                                              x, 128, fm_W + (size_t)r * 32768 + 64 * 128,
                                              cvecF, x, P1); // mx -> P1

    // ---- GCN stack ----
    k_deg<<<GN, 256, 0, stream>>>(indptr_m, eid_m, P6, scal, degb);
    k_gemm<64, 0><<<N / 16, 256, 0, stream>>>(P1, 128, gcn_W0 + (size_t)r * 8192,
                                              nullptr, 0, nullptr, nullptr, nullptr, P2); // xW0
    k_gcn<1><<<GN4, 256, 0, stream>>>(P2, indptr_m, src_m, eid_m, P6, scal, degb,
                                      gcn_b0 + r * 64, P4, 64); // z0
    k_gemm<64, 0><<<N / 16, 256, 0, stream>>>(P4, 64, gcn_W1 + (size_t)r * 4096,
                                              nullptr, 0, nullptr, nullptr, nullptr, P2); // xW1
    k_gcn<0><<<GN4, 256, 0, stream>>>(P2, indptr_m, src_m, eid_m, P6, scal, degb,
                                      gcn_b1 + r * 64, out_xtemp + r * 64, 192);
  }

  // ---- final linear + log_softmax ----
  k_logits<<<GN4, 256, 0, stream>>>(out_xtemp, lin_W, lin_b, out_lsm);
}

// Round 2
// 2789.582 us; speedup vs baseline: 1.1408x; 1.1408x over previous
//
#include <hip/hip_runtime.h>
#include <cstdint>

#define N_NODES 50000
#define FEAT    128
#define HID     64
#define NREL    3
#define NTREE   2
#define NEDGE   500000
#define NCLS    2

__device__ __forceinline__ float wave_red(float v){
  #pragma unroll
  for(int off = 32; off > 0; off >>= 1) v += __shfl_xor(v, off, 64);
  return v;
}

__device__ __forceinline__ unsigned short f2b(float f){
  unsigned int u = __float_as_uint(f);
  unsigned int r = (u + 0x7FFFu + ((u >> 16) & 1u)) >> 16;
  return (unsigned short)r;
}
__device__ __forceinline__ float b2f_lo(unsigned int u){ return __uint_as_float(u << 16); }
__device__ __forceinline__ float b2f_hi(unsigned int u){ return __uint_as_float(u & 0xFFFF0000u); }

// ---------------- batched CSR build (3 edge sets) ----------------
__global__ void k_hist3(const int* __restrict__ d0, const int* __restrict__ d1,
                        const int* __restrict__ d2, int E, int* __restrict__ counts){
  int s = blockIdx.y;
  const int* d = (s == 0) ? d0 : (s == 1) ? d1 : d2;
  int e = blockIdx.x * 256 + threadIdx.x;
  if(e < E) atomicAdd(&counts[s * N_NODES + d[e]], 1);
}

__global__ void k_scan1(const int* __restrict__ counts, int n,
                        int* __restrict__ indptr, int* __restrict__ blksum){
  __shared__ int sm[512];
  int s = blockIdx.y;
  int tid = threadIdx.x;
  int i = blockIdx.x * 512 + tid;
  int v = (i < n) ? counts[s * n + i] : 0;
  sm[tid] = v; __syncthreads();
  for(int off = 1; off < 512; off <<= 1){
    int t = (tid >= off) ? sm[tid - off] : 0;
    __syncthreads();
    sm[tid] += t;
    __syncthreads();
  }
  if(i < n) indptr[s * (n + 1) + i + 1] = sm[tid];
  if(tid == 511) blksum[s * 128 + blockIdx.x] = sm[511];
}

__global__ void k_scan2(int* blksum, int nb){
  int t = threadIdx.x;
  if(t < 3){
    int acc = 0;
    for(int b = 0; b < nb; b++){ int v = blksum[t * 128 + b]; blksum[t * 128 + b] = acc; acc += v; }
  }
}

__global__ void k_scan3(int* __restrict__ indptr, const int* __restrict__ blkoff, int n){
  int s = blockIdx.y;
  int i = blockIdx.x * 256 + threadIdx.x;
  if(i == 0) indptr[s * (n + 1)] = 0;
  if(i < n) indptr[s * (n + 1) + i + 1] += blkoff[s * 128 + (i >> 9)];
}

__global__ void k_fill3(const int* __restrict__ s0, const int* __restrict__ s1,
                        const int* __restrict__ s2, const int* __restrict__ d0,
                        const int* __restrict__ d1, const int* __restrict__ d2, int E,
                        const int* __restrict__ indptr, int* __restrict__ cursor,
                        int* __restrict__ csr_src){
  int s = blockIdx.y;
  const int* sp = (s == 0) ? s0 : (s == 1) ? s1 : s2;
  const int* dp = (s == 0) ? d0 : (s == 1) ? d1 : d2;
  int e = blockIdx.x * 256 + threadIdx.x;
  if(e < E){
    int d = dp[e];
    int p = indptr[s * (N_NODES + 1) + d] + atomicAdd(&cursor[s * N_NODES + d], 1);
    csr_src[s * NEDGE + p] = sp[e];
  }
}

// ---------------- mean aggregation over bf16 table (64-wide) ----------------
__global__ void k_agg64b(const unsigned short* __restrict__ TB, const int* __restrict__ indptr,
                         const int* __restrict__ csr_src, float* __restrict__ out){
  int lane = threadIdx.x & 63, wid = threadIdx.x >> 6;
  int node = blockIdx.x * 4 + wid;
  if(node >= N_NODES) return;
  int beg = indptr[node], end = indptr[node + 1];
  int cnt = end - beg;
  float sc = 1.0f / (float)(cnt >= 1 ? cnt : 1);
  float a = 0.f;
  for(int j = beg; j < end; j++){
    unsigned int u = (unsigned int)TB[(size_t)csr_src[j] * 64 + lane];
    a += __uint_as_float(u << 16);
  }
  out[(size_t)node * 64 + lane] = a * sc;
}

// ---------------- node GEMM: out = EPI(X1@W1 + X2@W2 + b) ----------------
// EPI: 0 none, 1 relu, 2 add, 3 add+relu, 4 mul-by-xmul. BF16OUT: write bf16.
template<int HOUT, int EPI, int BF16OUT>
__global__ void k_gemm2(const float* __restrict__ X1, int K1, const float* __restrict__ W1,
                        const float* __restrict__ X2, int K2, const float* __restrict__ W2,
                        const float* __restrict__ bias, const float* __restrict__ addv,
                        const float* __restrict__ xmul, void* __restrict__ outp){
  constexpr int NB = 32;
  constexpr int TC = HOUT / 4;     // thread-cols (16 or 32)
  constexpr int RG = 256 / TC;     // row groups  (16 or 8)
  constexpr int RPT = NB / RG;     // rows/thread (2 or 4)
  __shared__ float xs[NB][260];
  int tid = threadIdx.x;
  int node0 = blockIdx.x * NB;
  int K = K1 + K2, nf4 = K >> 2, K14 = K1 >> 2, K24 = K2 >> 2;
  for(int t = tid; t < NB * nf4; t += 256){
    int nd = t / nf4, q = t - nd * nf4;
    int node = node0 + nd; if(node >= N_NODES) node = N_NODES - 1;
    float4 v;
    if(q < K14) v = ((const float4*)X1)[(size_t)node * K14 + q];
    else        v = ((const float4*)X2)[(size_t)node * K24 + (q - K14)];
    *(float4*)&xs[nd][q * 4] = v;
  }
  __syncthreads();
  int c4 = (tid % TC) * 4;
  int rg = tid / TC;
  float4 acc[RPT];
  #pragma unroll
  for(int i = 0; i < RPT; i++){ acc[i].x = acc[i].y = acc[i].z = acc[i].w = 0.f; }

  const float* Ws[2] = {W1, W2};
  int Ks[2] = {K1, K2}, Ko[2] = {0, K1};
  #pragma unroll
  for(int part = 0; part < 2; part++){
    const float* W = Ws[part];
    int Kc = Ks[part], koff = Ko[part];
    for(int k4 = 0; k4 < Kc; k4 += 4){
      float4 xv[RPT];
      #pragma unroll
      for(int i = 0; i < RPT; i++) xv[i] = *(const float4*)&xs[rg * RPT + i][koff + k4];
      #pragma unroll
      for(int kk = 0; kk < 4; kk++){
        float4 w = *(const float4*)&W[(size_t)(k4 + kk) * HOUT + c4];
        #pragma unroll
        for(int i = 0; i < RPT; i++){
          float xvv = (kk == 0) ? xv[i].x : (kk == 1) ? xv[i].y : (kk == 2) ? xv[i].z : xv[i].w;
          acc[i].x += xvv * w.x; acc[i].y += xvv * w.y;
          acc[i].z += xvv * w.z; acc[i].w += xvv * w.w;
        }
      }
    }
  }

  float4 bv;
  if(bias) bv = *(const float4*)&bias[c4];
  else { bv.x = bv.y = bv.z = bv.w = 0.f; }
  #pragma unroll
  for(int i = 0; i < RPT; i++){
    int node = node0 + rg * RPT + i;
    if(node >= N_NODES) continue;
    float4 r;
    r.x = acc[i].x + bv.x; r.y = acc[i].y + bv.y;
    r.z = acc[i].z + bv.z; r.w = acc[i].w + bv.w;
    if(EPI == 2 || EPI == 3){
      float4 av = *(const float4*)&addv[(size_t)node * HOUT + c4];
      r.x += av.x; r.y += av.y; r.z += av.z; r.w += av.w;
    }
    if(EPI == 1 || EPI == 3){
      r.x = fmaxf(r.x, 0.f); r.y = fmaxf(r.y, 0.f);
      r.z = fmaxf(r.z, 0.f); r.w = fmaxf(r.w, 0.f);
    }
    if(EPI == 4){
      float4 mv = *(const float4*)&xmul[(size_t)node * HOUT + c4];
      r.x *= mv.x; r.y *= mv.y; r.z *= mv.z; r.w *= mv.w;
    }
    if(BF16OUT){
      ushort4 o; o.x = f2b(r.x); o.y = f2b(r.y); o.z = f2b(r.z); o.w = f2b(r.w);
      *(ushort4*)((unsigned short*)outp + (size_t)node * HOUT + c4) = o;
    } else {
      *(float4*)((float*)outp + (size_t)node * HOUT + c4) = r;
    }
  }
}

// ---------------- gating + lo ----------------
__global__ void k_gates_lo(const float* __restrict__ t0, const float* __restrict__ t1,
                           float* __restrict__ y,
                           const float* __restrict__ gate_W, const float* __restrict__ gate_b){
  int lane = threadIdx.x & 63, wid = threadIdx.x >> 6;
  int node = blockIdx.x * 4 + wid;
  if(node >= N_NODES) return;
  size_t idx = (size_t)node * 64 + lane;
  float t0v = t0[idx], t1v = t1[idx], yv = y[idx];
  float g0 = wave_red(t0v * gate_W[lane]) + gate_b[0];
  float g1 = wave_red(t1v * gate_W[64 + lane]) + gate_b[1];
  float m = fmaxf(g0, g1);
  float e0 = expf(g0 - m), e1 = expf(g1 - m);
  float a0 = e0 / (e0 + e1);
  y[idx] = yv + a0 * t0v + (1.f - a0) * t1v;
}

// ---------------- constant vectors ----------------
__global__ void k_cvec_e(const float* __restrict__ edge_emb, const float* __restrict__ ea_W1,
                         const float* __restrict__ ea_b1, float* __restrict__ cvec){
  int j = threadIdx.x;
  float s = ea_b1[j];
  for(int k = 0; k < 64; k++) s += edge_emb[k] * ea_W1[(128 + k) * 128 + j];
  cvec[j] = s;
}

__global__ void k_cvec_fm(const float* __restrict__ node_emb, const float* __restrict__ fm_W,
                          const float* __restrict__ fm_b, float* __restrict__ cvec){
  int j = threadIdx.x;
  float s = fm_b[j];
  for(int k = 0; k < 64; k++) s += node_emb[k] * fm_W[(192 + k) * 128 + j];
  cvec[j] = s;
}

// ---------------- per-edge MLP in CSR order (B streamed per node) ----------------
__global__ void k_em2(const unsigned int* __restrict__ A2, const unsigned int* __restrict__ B2,
                      const int* __restrict__ indptr, const int* __restrict__ csr_src,
                      const float* __restrict__ cvec, const float* __restrict__ W2,
                      const float* __restrict__ b2, float* __restrict__ em){
  int lane = threadIdx.x & 63, wid = threadIdx.x >> 6;
  int node = blockIdx.x * 4 + wid;
  if(node >= N_NODES) return;
  unsigned int bu = B2[(size_t)node * 64 + lane];
  float bl = b2f_lo(bu), bh = b2f_hi(bu);
  float2 c = ((const float2*)cvec)[lane];
  float2 w = ((const float2*)W2)[lane];
  float c0 = bl + c.x, c1 = bh + c.y;
  float b2v = b2[0];
  int beg = indptr[node], end = indptr[node + 1];
  for(int j = beg; j < end; j++){
    unsigned int au = A2[(size_t)csr_src[j] * 64 + lane];
    float h0 = fmaxf(b2f_lo(au) + c0, 0.f);
    float h1 = fmaxf(b2f_hi(au) + c1, 0.f);
    float r = wave_red(h0 * w.x + h1 * w.y);
    if(lane == 0) em[j] = r + b2v;
  }
}

// ---------------- min/max over em ----------------
__global__ void k_minmax_part(const float* __restrict__ em, int n,
                              float* __restrict__ pmn, float* __restrict__ pmx){
  __shared__ float smn[256], smx[256];
  int tid = threadIdx.x;
  float mn = 3.4e38f, mx = -3.4e38f;
  for(int i = blockIdx.x * 256 + tid; i < n; i += gridDim.x * 256){
    float v = em[i];
    mn = fminf(mn, v); mx = fmaxf(mx, v);
  }
  smn[tid] = mn; smx[tid] = mx; __syncthreads();
  for(int s = 128; s > 0; s >>= 1){
    if(tid < s){ smn[tid] = fminf(smn[tid], smn[tid + s]); smx[tid] = fmaxf(smx[tid], smx[tid + s]); }
    __syncthreads();
  }
  if(tid == 0){ pmn[blockIdx.x] = smn[0]; pmx[blockIdx.x] = smx[0]; }
}

__global__ void k_minmax_final(const float* __restrict__ pmn, const float* __restrict__ pmx,
                               int nb, float* __restrict__ scal){
  __shared__ float smn[256], smx[256];
  int tid = threadIdx.x;
  float mn = 3.4e38f, mx = -3.4e38f;
  if(tid < nb){ mn = pmn[tid]; mx = pmx[tid]; }
  smn[tid] = mn; smx[tid] = mx; __syncthreads();
  for(int s = 128; s > 0; s >>= 1){
    if(tid < s){ smn[tid] = fminf(smn[tid], smn[tid + s]); smx[tid] = fmaxf(smx[tid], smx[tid + s]); }
    __syncthreads();
  }
  if(tid == 0){
    scal[0] = smn[0];
    scal[1] = 1.0f / fmaxf(smx[0] - smn[0], 1e-30f);
  }
}

// ---------------- deg + dinv (streaming, CSR-order em) ----------------
__global__ void k_degdinv(const int* __restrict__ indptr, const float* __restrict__ em,
                          const float* __restrict__ scal, float* __restrict__ dinv){
  int i = blockIdx.x * 256 + threadIdx.x;
  if(i >= N_NODES) return;
  float mn = scal[0], inv = scal[1];
  float s = 1.f;
  int beg = indptr[i], end = indptr[i + 1];
  for(int j = beg; j < end; j++) s += (em[j] - mn) * inv;
  dinv[i] = rsqrtf(s);
}

// ---------------- GCN layer (gather, CSR-order em) ----------------
template<int RELU>
__global__ void k_gcn(const float* __restrict__ xW, const int* __restrict__ indptr,
                      const int* __restrict__ csr_src, const float* __restrict__ em,
                      const float* __restrict__ scal, const float* __restrict__ dinv,
                      const float* __restrict__ bias, float* __restrict__ out, int ostride){
  int lane = threadIdx.x & 63, wid = threadIdx.x >> 6;
  int node = blockIdx.x * 4 + wid;
  if(node >= N_NODES) return;
  float mn = scal[0], inv = scal[1];
  float di = dinv[node];
  float acc = 0.f;
  int beg = indptr[node], end = indptr[node + 1];
  for(int j = beg; j < end; j++){
    int s = csr_src[j];
    float w = (em[j] - mn) * inv;
    acc += w * dinv[s] * xW[(size_t)s * 64 + lane];
  }
  float r = acc * di + xW[(size_t)node * 64 + lane] * di * di + bias[lane];
  if(RELU) r = fmaxf(r, 0.f);
  out[(size_t)node * ostride + lane] = r;
}

// ---------------- logits + log_softmax ----------------
__global__ void k_logits(const float* __restrict__ xt, const float* __restrict__ lin_W,
                         const float* __restrict__ lin_b, float* __restrict__ out){
  int lane = threadIdx.x & 63, wid = threadIdx.x >> 6;
  int node = blockIdx.x * 4 + wid;
  if(node >= N_NODES) return;
  float a0 = 0.f, a1 = 0.f;
  #pragma unroll
  for(int q = 0; q < 3; q++){
    int k = q * 64 + lane;
    float v = xt[(size_t)node * 192 + k];
    a0 += v * lin_W[k * 2 + 0];
    a1 += v * lin_W[k * 2 + 1];
  }
  a0 = wave_red(a0);
  a1 = wave_red(a1);
  if(lane == 0){
    float l0 = fminf(fmaxf(a0 + lin_b[0], -1e10f), 1e10f);
    float l1 = fminf(fmaxf(a1 + lin_b[1], -1e10f), 1e10f);
    float m = fmaxf(l0, l1);
    float d = expf(l0 - m) + expf(l1 - m);
    float ls = m + logf(d);
    out[(size_t)node * 2 + 0] = l0 - ls;
    out[(size_t)node * 2 + 1] = l1 - ls;
  }
}

// =====================================================================
extern "C" void kernel_launch(void* const* d_in, const int* in_sizes, int n_in,
                              void* d_out, int out_size, void* d_ws, size_t ws_size,
                              hipStream_t stream){
  (void)in_sizes; (void)n_in; (void)out_size;
  const int N = N_NODES, E = NEDGE;

  const float* x        = (const float*)d_in[0];
  const int*  edge_main = (const int*)d_in[1];
  const int*  edge_tree = (const int*)d_in[2];
  const float* sage_Wl0 = (const float*)d_in[3];
  const float* sage_Wr0 = (const float*)d_in[4];
  const float* sage_b0  = (const float*)d_in[5];
  const float* sage_Wl1 = (const float*)d_in[6];
  const float* sage_Wr1 = (const float*)d_in[7];
  const float* sage_b1  = (const float*)d_in[8];
  const float* tree_Wl  = (const float*)d_in[9];
  const float* tree_Wr  = (const float*)d_in[10];
  const float* tree_b   = (const float*)d_in[11];
  const float* gate_W   = (const float*)d_in[12];
  const float* gate_b   = (const float*)d_in[13];
  const float* node_emb = (const float*)d_in[14];
  const float* edge_emb = (const float*)d_in[15];
  const float* fm_W     = (const float*)d_in[16];
  const float* fm_b     = (const float*)d_in[17];
  const float* ea_W1    = (const float*)d_in[18];
  const float* ea_b1    = (const float*)d_in[19];
  const float* ea_W2    = (const float*)d_in[20];
  const float* ea_b2    = (const float*)d_in[21];
  const float* gcn_W0   = (const float*)d_in[22];
  const float* gcn_b0   = (const float*)d_in[23];
  const float* gcn_W1   = (const float*)d_in[24];
  const float* gcn_b1   = (const float*)d_in[25];
  const float* lin_W    = (const float*)d_in[26];
  const float* lin_b    = (const float*)d_in[27];

  float* out_lsm   = (float*)d_out;
  float* out_xtemp = (float*)d_out + (size_t)N * NCLS;

  // ---- workspace (~93 MB) ----
  char* ws = (char*)d_ws;
  size_t off = 0;
  auto alloc = [&](size_t bytes) -> void* {
    off = (off + 255) & ~(size_t)255;
    void* p = ws + off;
    off += bytes;
    return p;
  };
  unsigned short* Abuf = (unsigned short*)alloc((size_t)N * 128 * 2 * 2); // A + B bf16; later mx f32
  unsigned short* Bbuf = Abuf + (size_t)N * 128;
  float* MX   = (float*)Abuf;                          // aliases A/B region
  float* BufA = (float*)alloc((size_t)N * 64 * 4);     // y0 / t0 / z0
  float* BufB = (float*)alloc((size_t)N * 64 * 4);     // t1
  float* LO   = (float*)alloc((size_t)N * 64 * 4);     // y -> lo
  float* AG   = (float*)alloc((size_t)N * 64 * 4);     // agg result / xW tables
  unsigned short* TBx = (unsigned short*)alloc((size_t)N * 64 * 2); // bf16 gather table
  float* em   = (float*)alloc((size_t)E * 4);
  float* dinv = (float*)alloc((size_t)N * 4);
  int* src3    = (int*)alloc((size_t)3 * E * 4);
  int* indptr3 = (int*)alloc((size_t)3 * (N + 1) * 4);
  int* counts3 = (int*)alloc((size_t)3 * N * 4);
  int* blk3    = (int*)alloc((size_t)3 * 128 * 4);
  float* cvecE = (float*)alloc(128 * 4);
  float* cvecF = (float*)alloc(128 * 4);
  float* pmn   = (float*)alloc(256 * 4);
  float* pmx   = (float*)alloc(256 * 4);
  float* scal  = (float*)alloc(8);
  if(ws_size < off) return;

  const int GE  = (E + 255) / 256;
  const int GN4 = (N + 3) / 4;
  const int GS1 = (N + 511) / 512;   // 98
  const int GN  = (N + 255) / 256;
  const int GG  = (N + 31) / 32;     // gemm grid (NB=32) = 1563

  for(int r = 0; r < NREL; r++){
    const int* sM  = edge_main + (size_t)r * 2 * E;
    const int* dM  = sM + E;
    const int* sT0 = edge_tree + ((size_t)(r * NTREE + 0) * 2) * E;
    const int* dT0 = sT0 + E;
    const int* sT1 = edge_tree + ((size_t)(r * NTREE + 1) * 2) * E;
    const int* dT1 = sT1 + E;

    // ---- batched CSR build: sets {main, tree0, tree1} ----
    hipMemsetAsync(counts3, 0, (size_t)3 * N * 4, stream);
    k_hist3<<<dim3(GE, 3), 256, 0, stream>>>(dM, dT0, dT1, E, counts3);
    k_scan1<<<dim3(GS1, 3), 512, 0, stream>>>(counts3, N, indptr3, blk3);
    k_scan2<<<1, 64, 0, stream>>>(blk3, GS1);
    k_scan3<<<dim3(GN, 3), 256, 0, stream>>>(indptr3, blk3, N);
    hipMemsetAsync(counts3, 0, (size_t)3 * N * 4, stream);
    k_fill3<<<dim3(GE, 3), 256, 0, stream>>>(sM, sT0, sT1, dM, dT0, dT1, E,
                                             indptr3, counts3, src3);
    const int* ipM  = indptr3;
    const int* ipT0 = indptr3 + (N + 1);
    const int* ipT1 = indptr3 + 2 * (N + 1);
    const int* csM  = src3;
    const int* csT0 = src3 + E;
    const int* csT1 = src3 + 2 * E;

    // ---- SAGE layer 0: y0 = relu(agg(x@Wl0) + x@Wr0 + b0) ----
    k_gemm2<64, 0, 1><<<GG, 256, 0, stream>>>(x, 128, sage_Wl0 + (size_t)r * 8192,
                                              nullptr, 0, nullptr, nullptr, nullptr, nullptr, TBx);
    k_agg64b<<<GN4, 256, 0, stream>>>(TBx, ipM, csM, AG);
    k_gemm2<64, 3, 0><<<GG, 256, 0, stream>>>(x, 128, sage_Wr0 + (size_t)r * 8192,
                                              nullptr, 0, nullptr, sage_b0 + r * 64, AG, nullptr, BufA);
    // ---- SAGE layer 1: y = agg(y0@Wl1) + y0@Wr1 + b1 ----
    k_gemm2<64, 0, 1><<<GG, 256, 0, stream>>>(BufA, 64, sage_Wl1 + (size_t)r * 4096,
                                              nullptr, 0, nullptr, nullptr, nullptr, nullptr, TBx);
    k_agg64b<<<GN4, 256, 0, stream>>>(TBx, ipM, csM, AG);
    k_gemm2<64, 2, 0><<<GG, 256, 0, stream>>>(BufA, 64, sage_Wr1 + (size_t)r * 4096,
                                              nullptr, 0, nullptr, sage_b1 + r * 64, AG, nullptr, LO);

    // ---- tree branches ----
    k_gemm2<64, 0, 1><<<GG, 256, 0, stream>>>(x, 128, tree_Wl + (size_t)(r * NTREE + 0) * 8192,
                                              nullptr, 0, nullptr, nullptr, nullptr, nullptr, TBx);
    k_agg64b<<<GN4, 256, 0, stream>>>(TBx, ipT0, csT0, AG);
    k_gemm2<64, 3, 0><<<GG, 256, 0, stream>>>(x, 128, tree_Wr + (size_t)(r * NTREE + 0) * 8192,
                                              nullptr, 0, nullptr, tree_b + (r * NTREE + 0) * 64, AG, nullptr, BufA);
    k_gemm2<64, 0, 1><<<GG, 256, 0, stream>>>(x, 128, tree_Wl + (size_t)(r * NTREE + 1) * 8192,
                                              nullptr, 0, nullptr, nullptr, nullptr, nullptr, TBx);
    k_agg64b<<<GN4, 256, 0, stream>>>(TBx, ipT1, csT1, AG);
    k_gemm2<64, 3, 0><<<GG, 256, 0, stream>>>(x, 128, tree_Wr + (size_t)(r * NTREE + 1) * 8192,
                                              nullptr, 0, nullptr, tree_b + (r * NTREE + 1) * 64, AG, nullptr, BufB);

    // ---- gating + lo (in place over LO) ----
    k_gates_lo<<<GN4, 256, 0, stream>>>(BufA, BufB, LO, gate_W + (size_t)r * 128, gate_b + r * 2);

    // ---- edge MLP (factored, CSR-order) ----
    k_cvec_e<<<1, 128, 0, stream>>>(edge_emb + r * 64, ea_W1, ea_b1, cvecE);
    k_gemm2<128, 0, 1><<<GG, 256, 0, stream>>>(LO, 64, ea_W1,
                                               nullptr, 0, nullptr, nullptr, nullptr, nullptr, Abuf);
    k_gemm2<128, 0, 1><<<GG, 256, 0, stream>>>(LO, 64, ea_W1 + 64 * 128,
                                               nullptr, 0, nullptr, nullptr, nullptr, nullptr, Bbuf);
    k_em2<<<GN4, 256, 0, stream>>>((const unsigned int*)Abuf, (const unsigned int*)Bbuf,
                                   ipM, csM, cvecE, ea_W2, ea_b2, em);
    k_minmax_part<<<256, 256, 0, stream>>>(em, E, pmn, pmx);
    k_minmax_final<<<1, 256, 0, stream>>>(pmn, pmx, 256, scal);

    // ---- feature mask: mx = x * (lo@fmW[0:64] + x@fmW[64:192] + cvecF) ----
    k_cvec_fm<<<1, 128, 0, stream>>>(node_emb + r * 64, fm_W + (size_t)r * 32768,
                                     fm_b + r * 128, cvecF);
    k_gemm2<128, 4, 0><<<GG, 256, 0, stream>>>(LO, 64, fm_W + (size_t)r * 32768,
                                               x, 128, fm_W + (size_t)r * 32768 + 64 * 128,
                                               cvecF, nullptr, x, MX);

    // ---- GCN stack ----
    k_degdinv<<<GN, 256, 0, stream>>>(ipM, em, scal, dinv);
    k_gemm2<64, 0, 0><<<GG, 256, 0, stream>>>(MX, 128, gcn_W0 + (size_t)r * 8192,
                                              nullptr, 0, nullptr, nullptr, nullptr, nullptr, AG);
    k_gcn<1><<<GN4, 256, 0, stream>>>(AG, ipM, csM, em, scal, dinv, gcn_b0 + r * 64, BufA, 64);
    k_gemm2<64, 0, 0><<<GG, 256, 0, stream>>>(BufA, 64, gcn_W1 + (size_t)r * 4096,
                                              nullptr, 0, nullptr, nullptr, nullptr, nullptr, AG);
    k_gcn<0><<<GN4, 256, 0, stream>>>(AG, ipM, csM, em, scal, dinv, gcn_b1 + r * 64,
                                      out_xtemp + r * 64, 192);
  }

  k_logits<<<GN4, 256, 0, stream>>>(out_xtemp, lin_W, lin_b, out_lsm);
}

// Round 3
// 2542.078 us; speedup vs baseline: 1.2518x; 1.0974x over previous
//
#include <hip/hip_runtime.h>
#include <cstdint>

#define N_NODES 50000
#define FEAT    128
#define HID     64
#define NREL    3
#define NTREE   2
#define NEDGE   500000
#define NCLS    2

#define BKT   391      // buckets of 128 nodes: ceil(50000/128)
#define CAP   1600     // per-bucket capacity (mean 1280, +9 sigma)
#define CHUNK 8192     // edges per pass-A block

__device__ __forceinline__ float wave_red(float v){
  #pragma unroll
  for(int off = 32; off > 0; off >>= 1) v += __shfl_xor(v, off, 64);
  return v;
}

__device__ __forceinline__ unsigned short f2b(float f){
  unsigned int u = __float_as_uint(f);
  unsigned int r = (u + 0x7FFFu + ((u >> 16) & 1u)) >> 16;
  return (unsigned short)r;
}
__device__ __forceinline__ float b2f_lo(unsigned int u){ return __uint_as_float(u << 16); }
__device__ __forceinline__ float b2f_hi(unsigned int u){ return __uint_as_float(u & 0xFFFF0000u); }

struct EdgePtrs { const int* s[9]; const int* d[9]; };

// ================= CSR build: bucketed two-pass, 9 sets batched =================
__global__ __launch_bounds__(256)
void k_passA(EdgePtrs ep, int* __restrict__ cursor, int* __restrict__ bucketed){
  int set = blockIdx.y;
  const int* src = ep.s[set];
  const int* dst = ep.d[set];
  __shared__ int hist[BKT];
  __shared__ int base[BKT];
  int tid = threadIdx.x;
  for(int b = tid; b < BKT; b += 256) hist[b] = 0;
  __syncthreads();
  int e0 = blockIdx.x * CHUNK;
  for(int i = tid; i < CHUNK; i += 256){
    int e = e0 + i;
    if(e < NEDGE) atomicAdd(&hist[dst[e] >> 7], 1);
  }
  __syncthreads();
  for(int b = tid; b < BKT; b += 256){
    int c = hist[b];
    base[b] = c ? atomicAdd(&cursor[set * BKT + b], c) : 0;
    hist[b] = 0;
  }
  __syncthreads();
  int* bk = bucketed + (size_t)set * BKT * CAP;
  for(int i = tid; i < CHUNK; i += 256){
    int e = e0 + i;
    if(e < NEDGE){
      int d = dst[e];
      int b = d >> 7;
      int rk = atomicAdd(&hist[b], 1);
      int pos = base[b] + rk;
      if(pos < CAP) bk[b * CAP + pos] = ((d & 127) << 16) | src[e];
    }
  }
}

__global__ void k_scanB(const int* __restrict__ cursor, int* __restrict__ bktbase,
                        int* __restrict__ indptr9){
  int set = blockIdx.x;
  __shared__ int sm[512];
  int tid = threadIdx.x;
  int v = (tid < BKT) ? cursor[set * BKT + tid] : 0;
  sm[tid] = v; __syncthreads();
  for(int off = 1; off < 512; off <<= 1){
    int t = (tid >= off) ? sm[tid - off] : 0;
    __syncthreads();
    sm[tid] += t;
    __syncthreads();
  }
  if(tid < BKT) bktbase[set * BKT + tid] = sm[tid] - v;
  if(tid == 0) indptr9[(size_t)set * (N_NODES + 1) + N_NODES] = NEDGE;
}

__global__ __launch_bounds__(256)
void k_passB(const int* __restrict__ bucketed, const int* __restrict__ cursor,
             const int* __restrict__ bktbase, int* __restrict__ indptr9,
             int* __restrict__ csr9){
  int set = blockIdx.y, b = blockIdx.x;
  int cnt = cursor[set * BKT + b]; if(cnt > CAP) cnt = CAP;
  int ebase = bktbase[set * BKT + b];
  const int* bk = bucketed + (size_t)set * BKT * CAP + b * CAP;
  __shared__ int pk[CAP];
  __shared__ int stage[CAP];
  __shared__ int h[128], sc[128], cur[128];
  int tid = threadIdx.x;
  for(int i = tid; i < cnt; i += 256) pk[i] = bk[i];
  if(tid < 128) h[tid] = 0;
  __syncthreads();
  for(int i = tid; i < cnt; i += 256) atomicAdd(&h[(pk[i] >> 16) & 127], 1);
  __syncthreads();
  if(tid < 128) sc[tid] = h[tid];
  __syncthreads();
  for(int off = 1; off < 128; off <<= 1){
    int t = 0;
    if(tid < 128 && tid >= off) t = sc[tid - off];
    __syncthreads();
    if(tid < 128) sc[tid] += t;
    __syncthreads();
  }
  if(tid < 128){
    int excl = sc[tid] - h[tid];
    cur[tid] = excl;
    int node = b * 128 + tid;
    if(node < N_NODES) indptr9[(size_t)set * (N_NODES + 1) + node] = ebase + excl;
  }
  __syncthreads();
  for(int i = tid; i < cnt; i += 256){
    int p = pk[i];
    int r = atomicAdd(&cur[(p >> 16) & 127], 1);
    stage[r] = p & 0xFFFF;
  }
  __syncthreads();
  int* out = csr9 + (size_t)set * NEDGE + ebase;
  for(int i = tid; i < cnt; i += 256) out[i] = stage[i];
}

// ================= mean aggregation over bf16 table slice =================
__global__ void k_agg64b(const unsigned short* __restrict__ TB, int tst, int goff,
                         const int* __restrict__ indptr, const int* __restrict__ csr_src,
                         float* __restrict__ out){
  int lane = threadIdx.x & 63, wid = threadIdx.x >> 6;
  int node = blockIdx.x * 4 + wid;
  if(node >= N_NODES) return;
  int beg = indptr[node], end = indptr[node + 1];
  int cnt = end - beg;
  float scv = 1.0f / (float)(cnt >= 1 ? cnt : 1);
  float a = 0.f;
  for(int j = beg; j < end; j++){
    unsigned int u = (unsigned int)TB[(size_t)csr_src[j] * tst + goff + lane];
    a += __uint_as_float(u << 16);
  }
  out[(size_t)node * 64 + lane] = a * scv;
}

// ================= generic multi-group node GEMM =================
// out[g] = [mul[g] *] [relu] (X@W[g] + b[g] [+ add[g]]),  groups of 64 output cols
struct GemmP {
  const float* W[4];
  const float* b[4];
  const float* add[4];
  const float* mul[4];
  void* out[4];
  int wst, ast, mst, ost;
};

template<int NGRP, int RELU, int HAS_ADD, int HAS_MUL, int BF16OUT>
__global__ __launch_bounds__(256)
void k_gemmN(const float* __restrict__ X1, int K1, int xs1_4,
             const float* __restrict__ X2, int K2, int xs2_4, GemmP P){
  __shared__ float xs[32][200];  // K <= 192 (+pad)
  int tid = threadIdx.x;
  int node0 = blockIdx.x * 32;
  int K = K1 + K2, nf4 = K >> 2, K14 = K1 >> 2;
  for(int t = tid; t < 32 * nf4; t += 256){
    int nd = t / nf4, q = t - nd * nf4;
    int node = node0 + nd; if(node >= N_NODES) node = N_NODES - 1;
    float4 v;
    if(q < K14) v = ((const float4*)X1)[(size_t)node * xs1_4 + q];
    else        v = ((const float4*)X2)[(size_t)node * xs2_4 + (q - K14)];
    *(float4*)&xs[nd][q * 4] = v;
  }
  __syncthreads();
  int c4 = (tid & 15) * 4, rg = tid >> 4;
  int r0 = rg * 2, r1 = r0 + 1;
  float4 acc[NGRP][2];
  #pragma unroll
  for(int g = 0; g < NGRP; g++){
    acc[g][0] = float4{0.f, 0.f, 0.f, 0.f};
    acc[g][1] = float4{0.f, 0.f, 0.f, 0.f};
  }
  for(int k4 = 0; k4 < K; k4 += 4){
    float4 a0 = *(const float4*)&xs[r0][k4];
    float4 a1 = *(const float4*)&xs[r1][k4];
    float xa0[4] = {a0.x, a0.y, a0.z, a0.w};
    float xa1[4] = {a1.x, a1.y, a1.z, a1.w};
    #pragma unroll
    for(int g = 0; g < NGRP; g++){
      #pragma unroll
      for(int kk = 0; kk < 4; kk++){
        float4 w = *(const float4*)&P.W[g][(size_t)(k4 + kk) * P.wst + c4];
        acc[g][0].x += xa0[kk] * w.x; acc[g][0].y += xa0[kk] * w.y;
        acc[g][0].z += xa0[kk] * w.z; acc[g][0].w += xa0[kk] * w.w;
        acc[g][1].x += xa1[kk] * w.x; acc[g][1].y += xa1[kk] * w.y;
        acc[g][1].z += xa1[kk] * w.z; acc[g][1].w += xa1[kk] * w.w;
      }
    }
  }
  #pragma unroll
  for(int g = 0; g < NGRP; g++){
    float4 bv = float4{0.f, 0.f, 0.f, 0.f};
    if(P.b[g]) bv = *(const float4*)&P.b[g][c4];
    #pragma unroll
    for(int i = 0; i < 2; i++){
      int node = node0 + r0 + i;
      if(node >= N_NODES) continue;
      float4 rr = acc[g][i];
      rr.x += bv.x; rr.y += bv.y; rr.z += bv.z; rr.w += bv.w;
      if(HAS_ADD){
        float4 av = *(const float4*)&P.add[g][(size_t)node * P.ast + c4];
        rr.x += av.x; rr.y += av.y; rr.z += av.z; rr.w += av.w;
      }
      if(RELU){
        rr.x = fmaxf(rr.x, 0.f); rr.y = fmaxf(rr.y, 0.f);
        rr.z = fmaxf(rr.z, 0.f); rr.w = fmaxf(rr.w, 0.f);
      }
      if(HAS_MUL){
        float4 mv = *(const float4*)&P.mul[g][(size_t)node * P.mst + c4];
        rr.x *= mv.x; rr.y *= mv.y; rr.z *= mv.z; rr.w *= mv.w;
      }
      if(BF16OUT){
        ushort4 o; o.x = f2b(rr.x); o.y = f2b(rr.y); o.z = f2b(rr.z); o.w = f2b(rr.w);
        *(ushort4*)((unsigned short*)P.out[g] + (size_t)node * P.ost + c4) = o;
      } else {
        *(float4*)((float*)P.out[g] + (size_t)node * P.ost + c4) = rr;
      }
    }
  }
}

// ================= gating + lo =================
__global__ void k_gates_lo(const float* __restrict__ t0, const float* __restrict__ t1,
                           float* __restrict__ y,
                           const float* __restrict__ gate_W, const float* __restrict__ gate_b){
  int lane = threadIdx.x & 63, wid = threadIdx.x >> 6;
  int node = blockIdx.x * 4 + wid;
  if(node >= N_NODES) return;
  size_t idx = (size_t)node * 64 + lane;
  float t0v = t0[idx], t1v = t1[idx], yv = y[idx];
  float g0 = wave_red(t0v * gate_W[lane]) + gate_b[0];
  float g1 = wave_red(t1v * gate_W[64 + lane]) + gate_b[1];
  float m = fmaxf(g0, g1);
  float e0 = expf(g0 - m), e1 = expf(g1 - m);
  float a0 = e0 / (e0 + e1);
  y[idx] = yv + a0 * t0v + (1.f - a0) * t1v;
}

// ================= constant vectors (both in one launch) =================
__global__ void k_cvec2(const float* __restrict__ ee, const float* __restrict__ ne,
                        const float* __restrict__ eaW1, const float* __restrict__ eab1,
                        const float* __restrict__ fmW, const float* __restrict__ fmb,
                        float* __restrict__ cE, float* __restrict__ cF){
  int j = threadIdx.x;
  if(blockIdx.x == 0){
    float s = eab1[j];
    for(int k = 0; k < 64; k++) s += ee[k] * eaW1[(128 + k) * 128 + j];
    cE[j] = s;
  } else {
    float s = fmb[j];
    for(int k = 0; k < 64; k++) s += ne[k] * fmW[(192 + k) * 128 + j];
    cF[j] = s;
  }
}

// ================= per-edge MLP in CSR order (packed bf16 A|B) =================
__global__ void k_em2(const unsigned int* __restrict__ AB,
                      const int* __restrict__ indptr, const int* __restrict__ csr_src,
                      const float* __restrict__ cvec, const float* __restrict__ W2,
                      const float* __restrict__ b2, float* __restrict__ em){
  int lane = threadIdx.x & 63, wid = threadIdx.x >> 6;
  int node = blockIdx.x * 4 + wid;
  if(node >= N_NODES) return;
  unsigned int bu = AB[(size_t)node * 128 + 64 + lane];
  float2 c = ((const float2*)cvec)[lane];
  float2 w = ((const float2*)W2)[lane];
  float c0 = b2f_lo(bu) + c.x, c1 = b2f_hi(bu) + c.y;
  float b2v = b2[0];
  int beg = indptr[node], end = indptr[node + 1];
  for(int j = beg; j < end; j++){
    unsigned int au = AB[(size_t)csr_src[j] * 128 + lane];
    float h0 = fmaxf(b2f_lo(au) + c0, 0.f);
    float h1 = fmaxf(b2f_hi(au) + c1, 0.f);
    float r = wave_red(h0 * w.x + h1 * w.y);
    if(lane == 0) em[j] = r + b2v;
  }
}

// ================= min/max over em =================
__global__ void k_minmax_part(const float* __restrict__ em, int n,
                              float* __restrict__ pmn, float* __restrict__ pmx){
  __shared__ float smn[256], smx[256];
  int tid = threadIdx.x;
  float mn = 3.4e38f, mx = -3.4e38f;
  for(int i = blockIdx.x * 256 + tid; i < n; i += gridDim.x * 256){
    float v = em[i];
    mn = fminf(mn, v); mx = fmaxf(mx, v);
  }
  smn[tid] = mn; smx[tid] = mx; __syncthreads();
  for(int s = 128; s > 0; s >>= 1){
    if(tid < s){ smn[tid] = fminf(smn[tid], smn[tid + s]); smx[tid] = fmaxf(smx[tid], smx[tid + s]); }
    __syncthreads();
  }
  if(tid == 0){ pmn[blockIdx.x] = smn[0]; pmx[blockIdx.x] = smx[0]; }
}

__global__ void k_minmax_final(const float* __restrict__ pmn, const float* __restrict__ pmx,
                               int nb, float* __restrict__ scal){
  __shared__ float smn[256], smx[256];
  int tid = threadIdx.x;
  float mn = 3.4e38f, mx = -3.4e38f;
  if(tid < nb){ mn = pmn[tid]; mx = pmx[tid]; }
  smn[tid] = mn; smx[tid] = mx; __syncthreads();
  for(int s = 128; s > 0; s >>= 1){
    if(tid < s){ smn[tid] = fminf(smn[tid], smn[tid + s]); smx[tid] = fmaxf(smx[tid], smx[tid + s]); }
    __syncthreads();
  }
  if(tid == 0){
    scal[0] = smn[0];
    scal[1] = 1.0f / fmaxf(smx[0] - smn[0], 1e-30f);
  }
}

// ================= deg^-1/2 =================
__global__ void k_degdinv(const int* __restrict__ indptr, const float* __restrict__ em,
                          const float* __restrict__ scal, float* __restrict__ dinv){
  int i = blockIdx.x * 256 + threadIdx.x;
  if(i >= N_NODES) return;
  float mn = scal[0], inv = scal[1];
  float s = 1.f;
  int beg = indptr[i], end = indptr[i + 1];
  for(int j = beg; j < end; j++) s += (em[j] - mn) * inv;
  dinv[i] = rsqrtf(s);
}

// ================= GCN layer (gather, CSR-order em) =================
template<int RELU>
__global__ void k_gcn(const float* __restrict__ xW, const int* __restrict__ indptr,
                      const int* __restrict__ csr_src, const float* __restrict__ em,
                      const float* __restrict__ scal, const float* __restrict__ dinv,
                      const float* __restrict__ bias, float* __restrict__ out, int ostride){
  int lane = threadIdx.x & 63, wid = threadIdx.x >> 6;
  int node = blockIdx.x * 4 + wid;
  if(node >= N_NODES) return;
  float mn = scal[0], inv = scal[1];
  float di = dinv[node];
  float acc = 0.f;
  int beg = indptr[node], end = indptr[node + 1];
  for(int j = beg; j < end; j++){
    int s = csr_src[j];
    float w = (em[j] - mn) * inv;
    acc += w * dinv[s] * xW[(size_t)s * 64 + lane];
  }
  float r = acc * di + xW[(size_t)node * 64 + lane] * di * di + bias[lane];
  if(RELU) r = fmaxf(r, 0.f);
  out[(size_t)node * ostride + lane] = r;
}

// ================= logits + log_softmax =================
__global__ void k_logits(const float* __restrict__ xt, const float* __restrict__ lin_W,
                         const float* __restrict__ lin_b, float* __restrict__ out){
  int lane = threadIdx.x & 63, wid = threadIdx.x >> 6;
  int node = blockIdx.x * 4 + wid;
  if(node >= N_NODES) return;
  float a0 = 0.f, a1 = 0.f;
  #pragma unroll
  for(int q = 0; q < 3; q++){
    int k = q * 64 + lane;
    float v = xt[(size_t)node * 192 + k];
    a0 += v * lin_W[k * 2 + 0];
    a1 += v * lin_W[k * 2 + 1];
  }
  a0 = wave_red(a0);
  a1 = wave_red(a1);
  if(lane == 0){
    float l0 = fminf(fmaxf(a0 + lin_b[0], -1e10f), 1e10f);
    float l1 = fminf(fmaxf(a1 + lin_b[1], -1e10f), 1e10f);
    float m = fmaxf(l0, l1);
    float d = expf(l0 - m) + expf(l1 - m);
    float ls = m + logf(d);
    out[(size_t)node * 2 + 0] = l0 - ls;
    out[(size_t)node * 2 + 1] = l1 - ls;
  }
}

// =====================================================================
extern "C" void kernel_launch(void* const* d_in, const int* in_sizes, int n_in,
                              void* d_out, int out_size, void* d_ws, size_t ws_size,
                              hipStream_t stream){
  (void)in_sizes; (void)n_in; (void)out_size;
  const int N = N_NODES, E = NEDGE;

  const float* x        = (const float*)d_in[0];
  const int*  edge_main = (const int*)d_in[1];
  const int*  edge_tree = (const int*)d_in[2];
  const float* sage_Wl0 = (const float*)d_in[3];
  const float* sage_Wr0 = (const float*)d_in[4];
  const float* sage_b0  = (const float*)d_in[5];
  const float* sage_Wl1 = (const float*)d_in[6];
  const float* sage_Wr1 = (const float*)d_in[7];
  const float* sage_b1  = (const float*)d_in[8];
  const float* tree_Wl  = (const float*)d_in[9];
  const float* tree_Wr  = (const float*)d_in[10];
  const float* tree_b   = (const float*)d_in[11];
  const float* gate_W   = (const float*)d_in[12];
  const float* gate_b   = (const float*)d_in[13];
  const float* node_emb = (const float*)d_in[14];
  const float* edge_emb = (const float*)d_in[15];
  const float* fm_W     = (const float*)d_in[16];
  const float* fm_b     = (const float*)d_in[17];
  const float* ea_W1    = (const float*)d_in[18];
  const float* ea_b1    = (const float*)d_in[19];
  const float* ea_W2    = (const float*)d_in[20];
  const float* ea_b2    = (const float*)d_in[21];
  const float* gcn_W0   = (const float*)d_in[22];
  const float* gcn_b0   = (const float*)d_in[23];
  const float* gcn_W1   = (const float*)d_in[24];
  const float* gcn_b1   = (const float*)d_in[25];
  const float* lin_W    = (const float*)d_in[26];
  const float* lin_b    = (const float*)d_in[27];

  float* out_lsm   = (float*)d_out;
  float* out_xtemp = (float*)d_out + (size_t)N * NCLS;

  // ---- workspace layout (~92.5 MB, phase-overlaid arena) ----
  char* ws = (char*)d_ws;
  // arena [0, 70.4MB): compute buffers; first 22.5MB doubles as `bucketed` in CSR phase
  unsigned short* TB3 = (unsigned short*)ws;           // bf16 [N,192] Wl-pack table / TBs / later Z
  float* AG  = (float*)(ws + 19200000);                // f32 [N,64] agg scratch / xW tables
  float* LOb = (float*)(ws + 32000000);                // f32 [N,64] y0 -> y -> lo (in-place)
  float* T0  = (float*)(ws + 44800000);                // f32 [N,64] tree0
  float* T1  = (float*)(ws + 57600000);                // f32 [N,64] tree1
  unsigned short* AB = (unsigned short*)(ws + 44800000); // bf16 [N,256] over T0|T1 (after gates)
  float* MX  = (float*)(ws + 44800000);                // f32 [N,128] over same (after em)
  float* Z   = (float*)ws;                             // f32 [N,64] over TB3 (gcn z0)
  int* bucketed = (int*)ws;                            // [9][391][1600] CSR phase only (22.5MB)
  int* csr9     = (int*)(ws + 70400000);               // 18MB
  int* indptr9  = (int*)(ws + 88400000);               // 1.8MB
  int* cursor   = (int*)(ws + 90200320);               // 14KB
  int* bktbase  = (int*)(ws + 90214656);               // 14KB
  float* em     = (float*)(ws + 90228992);             // 2MB
  float* dinv   = (float*)(ws + 92228992);             // 200KB
  float* cvecE  = (float*)(ws + 92428992);
  float* cvecF  = (float*)(ws + 92429504);
  float* pmn    = (float*)(ws + 92430016);
  float* pmx    = (float*)(ws + 92431040);
  float* scal   = (float*)(ws + 92432064);
  if(ws_size < 92433000) return;

  const int GN4 = (N + 3) / 4;
  const int GN  = (N + 255) / 256;
  const int GG  = (N + 31) / 32;
  const int NCH = (E + CHUNK - 1) / CHUNK;

  // ---- CSR build for all 9 edge sets ----
  EdgePtrs ep;
  for(int r = 0; r < NREL; r++){
    ep.s[r * 3 + 0] = edge_main + (size_t)r * 2 * E;
    ep.d[r * 3 + 0] = ep.s[r * 3 + 0] + E;
    for(int t = 0; t < NTREE; t++){
      ep.s[r * 3 + 1 + t] = edge_tree + ((size_t)(r * NTREE + t) * 2) * E;
      ep.d[r * 3 + 1 + t] = ep.s[r * 3 + 1 + t] + E;
    }
  }
  hipMemsetAsync(cursor, 0, 9 * BKT * 4, stream);
  k_passA<<<dim3(NCH, 9), 256, 0, stream>>>(ep, cursor, bucketed);
  k_scanB<<<9, 512, 0, stream>>>(cursor, bktbase, indptr9);
  k_passB<<<dim3(BKT, 9), 256, 0, stream>>>(bucketed, cursor, bktbase, indptr9, csr9);

  for(int r = 0; r < NREL; r++){
    const int* ipM = indptr9 + (size_t)(r * 3) * (N + 1);
    const int* csM = csr9 + (size_t)(r * 3) * E;

    // 1. Wl-pack: TB3 = bf16( x @ [sage_Wl0 | tree_Wl0 | tree_Wl1] )
    { GemmP p{}; p.wst = 64; p.ost = 192;
      p.W[0] = sage_Wl0 + (size_t)r * 8192;
      p.W[1] = tree_Wl + (size_t)(r * NTREE + 0) * 8192;
      p.W[2] = tree_Wl + (size_t)(r * NTREE + 1) * 8192;
      p.out[0] = TB3; p.out[1] = TB3 + 64; p.out[2] = TB3 + 128;
      k_gemmN<3, 0, 0, 0, 1><<<GG, 256, 0, stream>>>(x, 128, 32, nullptr, 0, 0, p); }

    // 2. per-branch: agg + Wr (+relu)
    for(int br = 0; br < 3; br++){
      const int* ip = indptr9 + (size_t)(r * 3 + br) * (N + 1);
      const int* cs = csr9 + (size_t)(r * 3 + br) * E;
      k_agg64b<<<GN4, 256, 0, stream>>>(TB3, 192, br * 64, ip, cs, AG);
      GemmP p{}; p.wst = 64; p.ast = 64; p.ost = 64;
      p.add[0] = AG;
      if(br == 0){ p.W[0] = sage_Wr0 + (size_t)r * 8192; p.b[0] = sage_b0 + r * 64; p.out[0] = LOb; }
      else { int t = br - 1;
        p.W[0] = tree_Wr + (size_t)(r * NTREE + t) * 8192;
        p.b[0] = tree_b + (size_t)(r * NTREE + t) * 64;
        p.out[0] = (t == 0) ? T0 : T1; }
      k_gemmN<1, 1, 1, 0, 0><<<GG, 256, 0, stream>>>(x, 128, 32, nullptr, 0, 0, p);
    }

    // 3. TBs = bf16(y0 @ Wl1) into TB3 region
    { GemmP p{}; p.wst = 64; p.ost = 64;
      p.W[0] = sage_Wl1 + (size_t)r * 4096; p.out[0] = TB3;
      k_gemmN<1, 0, 0, 0, 1><<<GG, 256, 0, stream>>>(LOb, 64, 16, nullptr, 0, 0, p); }
    // 4. AG = agg(TBs, main)
    k_agg64b<<<GN4, 256, 0, stream>>>(TB3, 64, 0, ipM, csM, AG);
    // 5. y = y0@Wr1 + AG + b1 (in-place over LOb; blocks only touch own rows)
    { GemmP p{}; p.wst = 64; p.ast = 64; p.ost = 64;
      p.W[0] = sage_Wr1 + (size_t)r * 4096; p.b[0] = sage_b1 + r * 64;
      p.add[0] = AG; p.out[0] = LOb;
      k_gemmN<1, 0, 1, 0, 0><<<GG, 256, 0, stream>>>(LOb, 64, 16, nullptr, 0, 0, p); }

    // 6. gating: lo = y + a0*t0 + a1*t1
    k_gates_lo<<<GN4, 256, 0, stream>>>(T0, T1, LOb, gate_W + (size_t)r * 128, gate_b + r * 2);

    // 7. constant vectors
    k_cvec2<<<2, 128, 0, stream>>>(edge_emb + r * 64, node_emb + r * 64, ea_W1, ea_b1,
                                   fm_W + (size_t)r * 32768, fm_b + r * 128, cvecE, cvecF);

    // 8. ea-pack: AB = bf16( lo @ [A0|A1|B0|B1] )
    { GemmP p{}; p.wst = 128; p.ost = 256;
      p.W[0] = ea_W1;            p.W[1] = ea_W1 + 64;
      p.W[2] = ea_W1 + 64 * 128; p.W[3] = ea_W1 + 64 * 128 + 64;
      p.out[0] = AB; p.out[1] = AB + 64; p.out[2] = AB + 128; p.out[3] = AB + 192;
      k_gemmN<4, 0, 0, 0, 1><<<GG, 256, 0, stream>>>(LOb, 64, 16, nullptr, 0, 0, p); }

    // 9-10. em + minmax
    k_em2<<<GN4, 256, 0, stream>>>((const unsigned int*)AB, ipM, csM, cvecE, ea_W2, ea_b2, em);
    k_minmax_part<<<256, 256, 0, stream>>>(em, E, pmn, pmx);
    k_minmax_final<<<1, 256, 0, stream>>>(pmn, pmx, 256, scal);

    // 11. feature mask: MX = x * (lo@fmW[0:64] + x@fmW[64:192] + cvecF)
    { GemmP p{}; p.wst = 128; p.mst = 128; p.ost = 128;
      const float* fw = fm_W + (size_t)r * 32768;
      p.W[0] = fw; p.W[1] = fw + 64;
      p.b[0] = cvecF; p.b[1] = cvecF + 64;
      p.mul[0] = x; p.mul[1] = x + 64;
      p.out[0] = MX; p.out[1] = MX + 64;
      k_gemmN<2, 0, 0, 1, 0><<<GG, 256, 0, stream>>>(LOb, 64, 16, x, 128, 32, p); }

    // 12. degrees
    k_degdinv<<<GN, 256, 0, stream>>>(ipM, em, scal, dinv);

    // 13-16. GCN stack
    { GemmP p{}; p.wst = 64; p.ost = 64;
      p.W[0] = gcn_W0 + (size_t)r * 8192; p.out[0] = AG;
      k_gemmN<1, 0, 0, 0, 0><<<GG, 256, 0, stream>>>(MX, 128, 32, nullptr, 0, 0, p); }
    k_gcn<1><<<GN4, 256, 0, stream>>>(AG, ipM, csM, em, scal, dinv, gcn_b0 + r * 64, Z, 64);
    { GemmP p{}; p.wst = 64; p.ost = 64;
      p.W[0] = gcn_W1 + (size_t)r * 4096; p.out[0] = AG;
      k_gemmN<1, 0, 0, 0, 0><<<GG, 256, 0, stream>>>(Z, 64, 16, nullptr, 0, 0, p); }
    k_gcn<0><<<GN4, 256, 0, stream>>>(AG, ipM, csM, em, scal, dinv, gcn_b1 + r * 64,
                                      out_xtemp + r * 64, 192);
  }

  k_logits<<<GN4, 256, 0, stream>>>(out_xtemp, lin_W, lin_b, out_lsm);
}

// Round 4
// 1278.315 us; speedup vs baseline: 2.4894x; 1.9886x over previous
//
#include <hip/hip_runtime.h>
#include <cstdint>

#define N_NODES 50000
#define FEAT    128
#define HID     64
#define NREL    3
#define NTREE   2
#define NEDGE   500000
#define NCLS    2

#define BKT   391
#define CAP   1600
#define CHUNK 8192

typedef __attribute__((ext_vector_type(8))) short bfrag;   // 8 bf16 (4 VGPR)
typedef __attribute__((ext_vector_type(4))) float ffrag;   // 4 f32 acc

__device__ __forceinline__ float wave_red(float v){
  #pragma unroll
  for(int off = 32; off > 0; off >>= 1) v += __shfl_xor(v, off, 64);
  return v;
}

__device__ __forceinline__ unsigned short f2b(float f){
  unsigned int u = __float_as_uint(f);
  unsigned int r = (u + 0x7FFFu + ((u >> 16) & 1u)) >> 16;
  return (unsigned short)r;
}
__device__ __forceinline__ float b2f_lo(unsigned int u){ return __uint_as_float(u << 16); }
__device__ __forceinline__ float b2f_hi(unsigned int u){ return __uint_as_float(u & 0xFFFF0000u); }
__device__ __forceinline__ float b2f(unsigned short s){ return __uint_as_float(((unsigned int)s) << 16); }

struct EdgePtrs { const int* s[9]; const int* d[9]; };

// ================= CSR build: bucketed two-pass, 9 sets batched =================
__global__ __launch_bounds__(256)
void k_passA(EdgePtrs ep, int* __restrict__ cursor, int* __restrict__ bucketed){
  int set = blockIdx.y;
  const int* src = ep.s[set];
  const int* dst = ep.d[set];
  __shared__ int hist[BKT];
  __shared__ int base[BKT];
  int tid = threadIdx.x;
  for(int b = tid; b < BKT; b += 256) hist[b] = 0;
  __syncthreads();
  int e0 = blockIdx.x * CHUNK;
  for(int i = tid; i < CHUNK; i += 256){
    int e = e0 + i;
    if(e < NEDGE) atomicAdd(&hist[dst[e] >> 7], 1);
  }
  __syncthreads();
  for(int b = tid; b < BKT; b += 256){
    int c = hist[b];
    base[b] = c ? atomicAdd(&cursor[set * BKT + b], c) : 0;
    hist[b] = 0;
  }
  __syncthreads();
  int* bk = bucketed + (size_t)set * BKT * CAP;
  for(int i = tid; i < CHUNK; i += 256){
    int e = e0 + i;
    if(e < NEDGE){
      int d = dst[e];
      int b = d >> 7;
      int rk = atomicAdd(&hist[b], 1);
      int pos = base[b] + rk;
      if(pos < CAP) bk[b * CAP + pos] = ((d & 127) << 16) | src[e];
    }
  }
}

__global__ void k_scanB(const int* __restrict__ cursor, int* __restrict__ bktbase,
                        int* __restrict__ indptr9){
  int set = blockIdx.x;
  __shared__ int sm[512];
  int tid = threadIdx.x;
  int v = (tid < BKT) ? cursor[set * BKT + tid] : 0;
  sm[tid] = v; __syncthreads();
  for(int off = 1; off < 512; off <<= 1){
    int t = (tid >= off) ? sm[tid - off] : 0;
    __syncthreads();
    sm[tid] += t;
    __syncthreads();
  }
  if(tid < BKT) bktbase[set * BKT + tid] = sm[tid] - v;
  if(tid == 0) indptr9[(size_t)set * (N_NODES + 1) + N_NODES] = NEDGE;
}

__global__ __launch_bounds__(256)
void k_passB(const int* __restrict__ bucketed, const int* __restrict__ cursor,
             const int* __restrict__ bktbase, int* __restrict__ indptr9,
             int* __restrict__ csr9){
  int set = blockIdx.y, b = blockIdx.x;
  int cnt = cursor[set * BKT + b]; if(cnt > CAP) cnt = CAP;
  int ebase = bktbase[set * BKT + b];
  const int* bk = bucketed + (size_t)set * BKT * CAP + b * CAP;
  __shared__ int pk[CAP];
  __shared__ int stage[CAP];
  __shared__ int h[128], sc[128], cur[128];
  int tid = threadIdx.x;
  for(int i = tid; i < cnt; i += 256) pk[i] = bk[i];
  if(tid < 128) h[tid] = 0;
  __syncthreads();
  for(int i = tid; i < cnt; i += 256) atomicAdd(&h[(pk[i] >> 16) & 127], 1);
  __syncthreads();
  if(tid < 128) sc[tid] = h[tid];
  __syncthreads();
  for(int off = 1; off < 128; off <<= 1){
    int t = 0;
    if(tid < 128 && tid >= off) t = sc[tid - off];
    __syncthreads();
    if(tid < 128) sc[tid] += t;
    __syncthreads();
  }
  if(tid < 128){
    int excl = sc[tid] - h[tid];
    cur[tid] = excl;
    int node = b * 128 + tid;
    if(node < N_NODES) indptr9[(size_t)set * (N_NODES + 1) + node] = ebase + excl;
  }
  __syncthreads();
  for(int i = tid; i < cnt; i += 256){
    int p = pk[i];
    int r = atomicAdd(&cur[(p >> 16) & 127], 1);
    stage[r] = p & 0xFFFF;
  }
  __syncthreads();
  int* out = csr9 + (size_t)set * NEDGE + ebase;
  for(int i = tid; i < cnt; i += 256) out[i] = stage[i];
}

// ================= f32 -> bf16 bulk convert =================
__global__ void k_tobf16(const float* __restrict__ in, unsigned short* __restrict__ o, int n4){
  int i = blockIdx.x * 256 + threadIdx.x;
  if(i < n4){
    float4 v = ((const float4*)in)[i];
    ushort4 u; u.x = f2b(v.x); u.y = f2b(v.y); u.z = f2b(v.z); u.w = f2b(v.w);
    ((ushort4*)o)[i] = u;
  }
}

// ================= weight pack: f32 W[k][c] -> bf16 Wt[(k>>3)*64+c][k&7] =================
struct PackJobs { const float* src[20]; int wst[20]; int K[20]; int dst[20]; int n; };

__global__ void k_wpack(PackJobs J, unsigned short* __restrict__ out){
  int j = blockIdx.x;
  if(j >= J.n) return;
  const float* s = J.src[j];
  int wst = J.wst[j], K = J.K[j];
  unsigned short* o = out + J.dst[j];
  for(int i = threadIdx.x; i < K * 64; i += 256){
    int k = i >> 6, c = i & 63;
    o[((((k >> 3) * 64) + c) << 3) + (k & 7)] = f2b(s[(size_t)k * wst + c]);
  }
}

// ================= MFMA node GEMM =================
// out[g] = [mul*] [relu] (X@Wt[g] + bias[g] [+ add[g]]); X = [X1 | X2] bf16
struct MG {
  const unsigned short* Wt[4];
  const float* bias[4];
  const float* add[4];
  const float* mul[4];
  void* out[4];
  int ast, mst, ost;
};

template<int K1, int K2, int NGRP, int RELU, int HAS_ADD, int HAS_MUL, int OUT_BF16>
__global__ __launch_bounds__(256)
void k_mgemm(const unsigned short* __restrict__ X1, int xs1,
             const unsigned short* __restrict__ X2, int xs2, MG P){
  constexpr int K = K1 + K2;
  constexpr int KS = K / 32;
  int tid = threadIdx.x;
  int lane = tid & 63;
  int w = tid >> 6;
  int row0 = blockIdx.x * 64 + w * 16;
  int l15 = lane & 15, kg = lane >> 4;
  int arow = row0 + l15; if(arow > N_NODES - 1) arow = N_NODES - 1;
  bfrag a[KS];
  #pragma unroll
  for(int ks = 0; ks < KS; ks++){
    int kk = ks * 32 + kg * 8;
    const unsigned short* p = (kk < K1) ? (X1 + (size_t)arow * xs1 + kk)
                                        : (X2 + (size_t)arow * xs2 + (kk - K1));
    a[ks] = *(const bfrag*)p;
  }
  int orow0 = row0 + kg * 4;
  #pragma unroll
  for(int g = 0; g < NGRP; g++){
    const unsigned short* Wg = P.Wt[g];
    #pragma unroll
    for(int ct = 0; ct < 4; ct++){
      int col = ct * 16 + l15;
      ffrag acc = {0.f, 0.f, 0.f, 0.f};
      #pragma unroll
      for(int ks = 0; ks < KS; ks++){
        bfrag bf = *(const bfrag*)(Wg + (((size_t)(ks * 4 + kg) * 64 + col) << 3));
        acc = __builtin_amdgcn_mfma_f32_16x16x32_bf16(a[ks], bf, acc, 0, 0, 0);
      }
      float bv = P.bias[g] ? P.bias[g][col] : 0.f;
      #pragma unroll
      for(int i = 0; i < 4; i++){
        int r = orow0 + i;
        if(r >= N_NODES) break;
        float v = acc[i] + bv;
        if(HAS_ADD) v += P.add[g][(size_t)r * P.ast + col];
        if(RELU) v = fmaxf(v, 0.f);
        if(HAS_MUL) v *= P.mul[g][(size_t)r * P.mst + col];
        if(OUT_BF16) ((unsigned short*)P.out[g])[(size_t)r * P.ost + col] = f2b(v);
        else         ((float*)P.out[g])[(size_t)r * P.ost + col] = v;
      }
    }
  }
}

// ================= mean aggregation over bf16 table (2 edges / wave-iter) =================
__global__ void k_agg64b(const unsigned short* __restrict__ TB, int tst, int goff,
                         const int* __restrict__ indptr, const int* __restrict__ csr_src,
                         float* __restrict__ out){
  int lane = threadIdx.x & 63, wid = threadIdx.x >> 6;
  int node = blockIdx.x * 4 + wid;
  if(node >= N_NODES) return;
  int c2 = lane & 31, h = lane >> 5;
  int beg = indptr[node], end = indptr[node + 1];
  int cnt = end - beg;
  float sc = 1.0f / (float)(cnt >= 1 ? cnt : 1);
  float a0 = 0.f, a1 = 0.f;
  for(int j = beg + h; j < end; j += 2){
    unsigned int u = *(const unsigned int*)(TB + (size_t)csr_src[j] * tst + goff + c2 * 2);
    a0 += b2f_lo(u); a1 += b2f_hi(u);
  }
  a0 += __shfl_xor(a0, 32, 64);
  a1 += __shfl_xor(a1, 32, 64);
  if(h == 0) *(float2*)&out[(size_t)node * 64 + c2 * 2] = float2{a0 * sc, a1 * sc};
}

// ================= gating + lo (bf16 trees, f32 y -> bf16 lo) =================
__global__ void k_gates_lo(const unsigned short* __restrict__ t0b, const unsigned short* __restrict__ t1b,
                           const float* __restrict__ y, const float* __restrict__ gate_W,
                           const float* __restrict__ gate_b, unsigned short* __restrict__ lo){
  int lane = threadIdx.x & 63, wid = threadIdx.x >> 6;
  int node = blockIdx.x * 4 + wid;
  if(node >= N_NODES) return;
  size_t idx = (size_t)node * 64 + lane;
  float t0v = b2f(t0b[idx]), t1v = b2f(t1b[idx]), yv = y[idx];
  float g0 = wave_red(t0v * gate_W[lane]) + gate_b[0];
  float g1 = wave_red(t1v * gate_W[64 + lane]) + gate_b[1];
  float m = fmaxf(g0, g1);
  float e0 = expf(g0 - m), e1 = expf(g1 - m);
  float a0 = e0 / (e0 + e1);
  lo[idx] = f2b(yv + a0 * t0v + (1.f - a0) * t1v);
}

// ================= constant vectors =================
__global__ void k_cvec2(const float* __restrict__ ee, const float* __restrict__ ne,
                        const float* __restrict__ eaW1, const float* __restrict__ eab1,
                        const float* __restrict__ fmW, const float* __restrict__ fmb,
                        float* __restrict__ cE, float* __restrict__ cF){
  int j = threadIdx.x;
  if(blockIdx.x == 0){
    float s = eab1[j];
    for(int k = 0; k < 64; k++) s += ee[k] * eaW1[(128 + k) * 128 + j];
    cE[j] = s;
  } else {
    float s = fmb[j];
    for(int k = 0; k < 64; k++) s += ne[k] * fmW[(192 + k) * 128 + j];
    cF[j] = s;
  }
}

// ================= per-edge MLP in CSR order (packed bf16 A|B) =================
__global__ void k_em2(const unsigned int* __restrict__ AB,
                      const int* __restrict__ indptr, const int* __restrict__ csr_src,
                      const float* __restrict__ cvec, const float* __restrict__ W2,
                      const float* __restrict__ b2, float* __restrict__ em){
  int lane = threadIdx.x & 63, wid = threadIdx.x >> 6;
  int node = blockIdx.x * 4 + wid;
  if(node >= N_NODES) return;
  unsigned int bu = AB[(size_t)node * 128 + 64 + lane];
  float2 c = ((const float2*)cvec)[lane];
  float2 w = ((const float2*)W2)[lane];
  float c0 = b2f_lo(bu) + c.x, c1 = b2f_hi(bu) + c.y;
  float b2v = b2[0];
  int beg = indptr[node], end = indptr[node + 1];
  for(int j = beg; j < end; j++){
    unsigned int au = AB[(size_t)csr_src[j] * 128 + lane];
    float h0 = fmaxf(b2f_lo(au) + c0, 0.f);
    float h1 = fmaxf(b2f_hi(au) + c1, 0.f);
    float r = wave_red(h0 * w.x + h1 * w.y);
    if(lane == 0) em[j] = r + b2v;
  }
}

// ================= min/max over em =================
__global__ void k_minmax_part(const float* __restrict__ em, int n,
                              float* __restrict__ pmn, float* __restrict__ pmx){
  __shared__ float smn[256], smx[256];
  int tid = threadIdx.x;
  float mn = 3.4e38f, mx = -3.4e38f;
  for(int i = blockIdx.x * 256 + tid; i < n; i += gridDim.x * 256){
    float v = em[i];
    mn = fminf(mn, v); mx = fmaxf(mx, v);
  }
  smn[tid] = mn; smx[tid] = mx; __syncthreads();
  for(int s = 128; s > 0; s >>= 1){
    if(tid < s){ smn[tid] = fminf(smn[tid], smn[tid + s]); smx[tid] = fmaxf(smx[tid], smx[tid + s]); }
    __syncthreads();
  }
  if(tid == 0){ pmn[blockIdx.x] = smn[0]; pmx[blockIdx.x] = smx[0]; }
}

__global__ void k_minmax_final(const float* __restrict__ pmn, const float* __restrict__ pmx,
                               int nb, float* __restrict__ scal){
  __shared__ float smn[256], smx[256];
  int tid = threadIdx.x;
  float mn = 3.4e38f, mx = -3.4e38f;
  if(tid < nb){ mn = pmn[tid]; mx = pmx[tid]; }
  smn[tid] = mn; smx[tid] = mx; __syncthreads();
  for(int s = 128; s > 0; s >>= 1){
    if(tid < s){ smn[tid] = fminf(smn[tid], smn[tid + s]); smx[tid] = fmaxf(smx[tid], smx[tid + s]); }
    __syncthreads();
  }
  if(tid == 0){
    scal[0] = smn[0];
    scal[1] = 1.0f / fmaxf(smx[0] - smn[0], 1e-30f);
  }
}

// ================= deg^-1/2 =================
__global__ void k_degdinv(const int* __restrict__ indptr, const float* __restrict__ em,
                          const float* __restrict__ scal, float* __restrict__ dinv){
  int i = blockIdx.x * 256 + threadIdx.x;
  if(i >= N_NODES) return;
  float mn = scal[0], inv = scal[1];
  float s = 1.f;
  int beg = indptr[i], end = indptr[i + 1];
  for(int j = beg; j < end; j++) s += (em[j] - mn) * inv;
  dinv[i] = rsqrtf(s);
}

// ================= GCN layer (bf16 xW gather, 2 edges / wave-iter) =================
template<int RELU, int OUTB>
__global__ void k_gcn(const unsigned int* __restrict__ xW2, const int* __restrict__ indptr,
                      const int* __restrict__ csr_src, const float* __restrict__ em,
                      const float* __restrict__ scal, const float* __restrict__ dinv,
                      const float* __restrict__ bias, void* __restrict__ out, int ostride){
  int lane = threadIdx.x & 63, wid = threadIdx.x >> 6;
  int node = blockIdx.x * 4 + wid;
  if(node >= N_NODES) return;
  int c2 = lane & 31, h = lane >> 5;
  float mn = scal[0], inv = scal[1];
  float di = dinv[node];
  float a0 = 0.f, a1 = 0.f;
  int beg = indptr[node], end = indptr[node + 1];
  for(int j = beg + h; j < end; j += 2){
    int s = csr_src[j];
    float wv = (em[j] - mn) * inv * dinv[s];
    unsigned int u = xW2[(size_t)s * 32 + c2];
    a0 += wv * b2f_lo(u);
    a1 += wv * b2f_hi(u);
  }
  a0 += __shfl_xor(a0, 32, 64);
  a1 += __shfl_xor(a1, 32, 64);
  if(h == 0){
    unsigned int su = xW2[(size_t)node * 32 + c2];
    float r0 = a0 * di + b2f_lo(su) * di * di + bias[c2 * 2];
    float r1 = a1 * di + b2f_hi(su) * di * di + bias[c2 * 2 + 1];
    if(RELU){ r0 = fmaxf(r0, 0.f); r1 = fmaxf(r1, 0.f); }
    if(OUTB){
      unsigned int* o = (unsigned int*)out;
      o[((size_t)node * ostride + c2 * 2) >> 1] = ((unsigned int)f2b(r1) << 16) | f2b(r0);
    } else {
      float* o = (float*)out;
      *(float2*)&o[(size_t)node * ostride + c2 * 2] = float2{r0, r1};
    }
  }
}

// ================= logits + log_softmax =================
__global__ void k_logits(const float* __restrict__ xt, const float* __restrict__ lin_W,
                         const float* __restrict__ lin_b, float* __restrict__ out){
  int lane = threadIdx.x & 63, wid = threadIdx.x >> 6;
  int node = blockIdx.x * 4 + wid;
  if(node >= N_NODES) return;
  float a0 = 0.f, a1 = 0.f;
  #pragma unroll
  for(int q = 0; q < 3; q++){
    int k = q * 64 + lane;
    float v = xt[(size_t)node * 192 + k];
    a0 += v * lin_W[k * 2 + 0];
    a1 += v * lin_W[k * 2 + 1];
  }
  a0 = wave_red(a0);
  a1 = wave_red(a1);
  if(lane == 0){
    float l0 = fminf(fmaxf(a0 + lin_b[0], -1e10f), 1e10f);
    float l1 = fminf(fmaxf(a1 + lin_b[1], -1e10f), 1e10f);
    float m = fmaxf(l0, l1);
    float d = expf(l0 - m) + expf(l1 - m);
    float ls = m + logf(d);
    out[(size_t)node * 2 + 0] = l0 - ls;
    out[(size_t)node * 2 + 1] = l1 - ls;
  }
}

// =====================================================================
extern "C" void kernel_launch(void* const* d_in, const int* in_sizes, int n_in,
                              void* d_out, int out_size, void* d_ws, size_t ws_size,
                              hipStream_t stream){
  (void)in_sizes; (void)n_in; (void)out_size;
  const int N = N_NODES, E = NEDGE;

  const float* x        = (const float*)d_in[0];
  const int*  edge_main = (const int*)d_in[1];
  const int*  edge_tree = (const int*)d_in[2];
  const float* sage_Wl0 = (const float*)d_in[3];
  const float* sage_Wr0 = (const float*)d_in[4];
  const float* sage_b0  = (const float*)d_in[5];
  const float* sage_Wl1 = (const float*)d_in[6];
  const float* sage_Wr1 = (const float*)d_in[7];
  const float* sage_b1  = (const float*)d_in[8];
  const float* tree_Wl  = (const float*)d_in[9];
  const float* tree_Wr  = (const float*)d_in[10];
  const float* tree_b   = (const float*)d_in[11];
  const float* gate_W   = (const float*)d_in[12];
  const float* gate_b   = (const float*)d_in[13];
  const float* node_emb = (const float*)d_in[14];
  const float* edge_emb = (const float*)d_in[15];
  const float* fm_W     = (const float*)d_in[16];
  const float* fm_b     = (const float*)d_in[17];
  const float* ea_W1    = (const float*)d_in[18];
  const float* ea_b1    = (const float*)d_in[19];
  const float* ea_W2    = (const float*)d_in[20];
  const float* ea_b2    = (const float*)d_in[21];
  const float* gcn_W0   = (const float*)d_in[22];
  const float* gcn_b0   = (const float*)d_in[23];
  const float* gcn_W1   = (const float*)d_in[24];
  const float* gcn_b1   = (const float*)d_in[25];
  const float* lin_W    = (const float*)d_in[26];
  const float* lin_b    = (const float*)d_in[27];

  float* out_lsm   = (float*)d_out;
  float* out_xtemp = (float*)d_out + (size_t)N * NCLS;

  // ---- workspace layout (~99.4 MB, phase-overlaid) ----
  char* ws = (char*)d_ws;
  unsigned short* TB3  = (unsigned short*)(ws + 0);          // bf16 [N,192] Wl-pack table
  float*          AG   = (float*)(ws + 19200000);            // f32 [N,64] agg scratch
  unsigned short* xb   = (unsigned short*)(ws + 32000000);   // bf16 [N,128] (persistent)
  unsigned short* y0b  = (unsigned short*)(ws + 44800000);   // bf16 [N,64]
  unsigned short* T0b  = (unsigned short*)(ws + 51200000);   // bf16 [N,64]
  unsigned short* T1b  = (unsigned short*)(ws + 57600000);   // bf16 [N,64]
  unsigned short* AB   = (unsigned short*)(ws + 44800000);   // bf16 [N,256] (after gates)
  unsigned short* MXb  = (unsigned short*)(ws + 44800000);   // bf16 [N,128] (after em)
  unsigned short* LOb  = (unsigned short*)(ws + 70400000);   // bf16 [N,64] lo
  unsigned short* TBs  = (unsigned short*)(ws + 0);          // bf16 [N,64] (over TB3, after step2)
  float*          Y    = (float*)(ws + 6400000);             // f32 [N,64] (over TB3)
  unsigned short* xW0b = (unsigned short*)(ws + 0);          // bf16 [N,64] (gcn phase)
  unsigned short* z0b  = (unsigned short*)(ws + 6400000);    // bf16 [N,64]
  unsigned short* xW1b = (unsigned short*)(ws + 12800000);   // bf16 [N,64]
  unsigned short* Wpk  = (unsigned short*)(ws + 76800000);   // bf16 packed weights (~0.6MB)
  int*   bucketed = (int*)(ws + 0);                          // [9][BKT][CAP] CSR phase only
  int*   csr9     = (int*)(ws + 77400064);                   // 18MB
  int*   indptr9  = (int*)(ws + 95400064);                   // 1.8MB
  float* em       = (float*)(ws + 97200384);                 // 2MB
  float* dinv     = (float*)(ws + 99200384);                 // 200KB
  int*   cursor   = (int*)(ws + 99400448);
  int*   bktbase  = (int*)(ws + 99414784);
  float* cvecE    = (float*)(ws + 99429120);
  float* cvecF    = (float*)(ws + 99429632);
  float* pmn      = (float*)(ws + 99430144);
  float* pmx      = (float*)(ws + 99431168);
  float* scal     = (float*)(ws + 99432192);
  if(ws_size < 99432704) return;

  const int GN4 = (N + 3) / 4;
  const int GN  = (N + 255) / 256;
  const int GGM = (N + 63) / 64;       // mfma gemm grid = 782
  const int NCH = (E + CHUNK - 1) / CHUNK;

  // ---- weight pack jobs ----
  PackJobs PJ[2]; PJ[0].n = 0; PJ[1].n = 0;
  int npj = 0, dstElem = 0;
  const unsigned short* WlpA[NREL]; const unsigned short* WlpB[NREL]; const unsigned short* WlpC[NREL];
  const unsigned short* Wr0j[NREL]; const unsigned short* WrT0[NREL]; const unsigned short* WrT1[NREL];
  const unsigned short* Wl1j[NREL]; const unsigned short* Wr1j[NREL];
  const unsigned short* Fm0j[NREL]; const unsigned short* Fm1j[NREL];
  const unsigned short* G0j[NREL];  const unsigned short* G1j[NREL];
  const unsigned short *EaA0, *EaA1, *EaB0, *EaB1;
  auto addjob = [&](const float* src, int wst, int K) -> const unsigned short* {
    int slot = npj < 20 ? 0 : 1;
    int k = npj - slot * 20;
    PJ[slot].src[k] = src; PJ[slot].wst[k] = wst; PJ[slot].K[k] = K; PJ[slot].dst[k] = dstElem;
    PJ[slot].n = k + 1;
    const unsigned short* ret = Wpk + dstElem;
    dstElem += K * 64; npj++;
    return ret;
  };
  for(int r = 0; r < NREL; r++){
    WlpA[r] = addjob(sage_Wl0 + (size_t)r * 8192, 64, 128);
    WlpB[r] = addjob(tree_Wl + (size_t)(r * NTREE + 0) * 8192, 64, 128);
    WlpC[r] = addjob(tree_Wl + (size_t)(r * NTREE + 1) * 8192, 64, 128);
    Wr0j[r] = addjob(sage_Wr0 + (size_t)r * 8192, 64, 128);
    WrT0[r] = addjob(tree_Wr + (size_t)(r * NTREE + 0) * 8192, 64, 128);
    WrT1[r] = addjob(tree_Wr + (size_t)(r * NTREE + 1) * 8192, 64, 128);
    Wl1j[r] = addjob(sage_Wl1 + (size_t)r * 4096, 64, 64);
    Wr1j[r] = addjob(sage_Wr1 + (size_t)r * 4096, 64, 64);
    Fm0j[r] = addjob(fm_W + (size_t)r * 32768, 128, 192);
    Fm1j[r] = addjob(fm_W + (size_t)r * 32768 + 64, 128, 192);
    G0j[r]  = addjob(gcn_W0 + (size_t)r * 8192, 64, 128);
    G1j[r]  = addjob(gcn_W1 + (size_t)r * 4096, 64, 64);
  }
  EaA0 = addjob(ea_W1, 128, 64);
  EaA1 = addjob(ea_W1 + 64, 128, 64);
  EaB0 = addjob(ea_W1 + 64 * 128, 128, 64);
  EaB1 = addjob(ea_W1 + 64 * 128 + 64, 128, 64);

  // ---- CSR build for all 9 edge sets ----
  EdgePtrs ep;
  for(int r = 0; r < NREL; r++){
    ep.s[r * 3 + 0] = edge_main + (size_t)r * 2 * E;
    ep.d[r * 3 + 0] = ep.s[r * 3 + 0] + E;
    for(int t = 0; t < NTREE; t++){
      ep.s[r * 3 + 1 + t] = edge_tree + ((size_t)(r * NTREE + t) * 2) * E;
      ep.d[r * 3 + 1 + t] = ep.s[r * 3 + 1 + t] + E;
    }
  }
  hipMemsetAsync(cursor, 0, 9 * BKT * 4, stream);
  k_passA<<<dim3(NCH, 9), 256, 0, stream>>>(ep, cursor, bucketed);
  k_scanB<<<9, 512, 0, stream>>>(cursor, bktbase, indptr9);
  k_passB<<<dim3(BKT, 9), 256, 0, stream>>>(bucketed, cursor, bktbase, indptr9, csr9);

  // ---- one-time conversions (after CSR: they overlay nothing used by CSR) ----
  k_wpack<<<PJ[0].n, 256, 0, stream>>>(PJ[0], Wpk);
  k_wpack<<<PJ[1].n, 256, 0, stream>>>(PJ[1], Wpk);
  k_tobf16<<<(N * 128 / 4 + 255) / 256, 256, 0, stream>>>(x, xb, N * 128 / 4);

  for(int r = 0; r < NREL; r++){
    const int* ipM = indptr9 + (size_t)(r * 3) * (N + 1);
    const int* csM = csr9 + (size_t)(r * 3) * E;

    // 1. Wl-pack: TB3 = bf16( x @ [sage_Wl0 | tree_Wl0 | tree_Wl1] )
    { MG p{}; p.ost = 192;
      p.Wt[0] = WlpA[r]; p.Wt[1] = WlpB[r]; p.Wt[2] = WlpC[r];
      p.out[0] = TB3; p.out[1] = TB3 + 64; p.out[2] = TB3 + 128;
      k_mgemm<128, 0, 3, 0, 0, 0, 1><<<GGM, 256, 0, stream>>>(xb, 128, nullptr, 0, p); }

    // 2. per-branch: agg + x@Wr + relu
    for(int br = 0; br < 3; br++){
      const int* ip = indptr9 + (size_t)(r * 3 + br) * (N + 1);
      const int* cs = csr9 + (size_t)(r * 3 + br) * E;
      k_agg64b<<<GN4, 256, 0, stream>>>(TB3, 192, br * 64, ip, cs, AG);
      MG p{}; p.ast = 64; p.ost = 64;
      p.add[0] = AG;
      if(br == 0){ p.Wt[0] = Wr0j[r]; p.bias[0] = sage_b0 + r * 64; p.out[0] = y0b; }
      else if(br == 1){ p.Wt[0] = WrT0[r]; p.bias[0] = tree_b + (size_t)(r * NTREE) * 64; p.out[0] = T0b; }
      else { p.Wt[0] = WrT1[r]; p.bias[0] = tree_b + (size_t)(r * NTREE + 1) * 64; p.out[0] = T1b; }
      k_mgemm<128, 0, 1, 1, 1, 0, 1><<<GGM, 256, 0, stream>>>(xb, 128, nullptr, 0, p);
    }

    // 3. TBs = bf16(y0 @ Wl1)
    { MG p{}; p.ost = 64; p.Wt[0] = Wl1j[r]; p.out[0] = TBs;
      k_mgemm<64, 0, 1, 0, 0, 0, 1><<<GGM, 256, 0, stream>>>(y0b, 64, nullptr, 0, p); }
    // 4. AG = agg(TBs, main)
    k_agg64b<<<GN4, 256, 0, stream>>>(TBs, 64, 0, ipM, csM, AG);
    // 5. Y = y0 @ Wr1 + AG + b1  (f32)
    { MG p{}; p.ast = 64; p.ost = 64;
      p.Wt[0] = Wr1j[r]; p.bias[0] = sage_b1 + r * 64; p.add[0] = AG; p.out[0] = Y;
      k_mgemm<64, 0, 1, 0, 1, 0, 0><<<GGM, 256, 0, stream>>>(y0b, 64, nullptr, 0, p); }

    // 6. gating: lo = y + a0*t0 + a1*t1 -> bf16
    k_gates_lo<<<GN4, 256, 0, stream>>>(T0b, T1b, Y, gate_W + (size_t)r * 128, gate_b + r * 2, LOb);

    // 7. constant vectors
    k_cvec2<<<2, 128, 0, stream>>>(edge_emb + r * 64, node_emb + r * 64, ea_W1, ea_b1,
                                   fm_W + (size_t)r * 32768, fm_b + r * 128, cvecE, cvecF);

    // 8. ea-pack: AB = bf16( lo @ [A0|A1|B0|B1] )
    { MG p{}; p.ost = 256;
      p.Wt[0] = EaA0; p.Wt[1] = EaA1; p.Wt[2] = EaB0; p.Wt[3] = EaB1;
      p.out[0] = AB; p.out[1] = AB + 64; p.out[2] = AB + 128; p.out[3] = AB + 192;
      k_mgemm<64, 0, 4, 0, 0, 0, 1><<<GGM, 256, 0, stream>>>(LOb, 64, nullptr, 0, p); }

    // 9-10. em + minmax
    k_em2<<<GN4, 256, 0, stream>>>((const unsigned int*)AB, ipM, csM, cvecE, ea_W2, ea_b2, em);
    k_minmax_part<<<256, 256, 0, stream>>>(em, E, pmn, pmx);
    k_minmax_final<<<1, 256, 0, stream>>>(pmn, pmx, 256, scal);

    // 11. feature mask: MXb = bf16( x * ([lo|x]@fmW + cvecF) )
    { MG p{}; p.mst = 128; p.ost = 128;
      p.Wt[0] = Fm0j[r]; p.Wt[1] = Fm1j[r];
      p.bias[0] = cvecF; p.bias[1] = cvecF + 64;
      p.mul[0] = x; p.mul[1] = x + 64;
      p.out[0] = MXb; p.out[1] = MXb + 64;
      k_mgemm<64, 128, 2, 0, 0, 1, 1><<<GGM, 256, 0, stream>>>(LOb, 64, xb, 128, p); }

    // 12. degrees
    k_degdinv<<<GN, 256, 0, stream>>>(ipM, em, scal, dinv);

    // 13-16. GCN stack
    { MG p{}; p.ost = 64; p.Wt[0] = G0j[r]; p.out[0] = xW0b;
      k_mgemm<128, 0, 1, 0, 0, 0, 1><<<GGM, 256, 0, stream>>>(MXb, 128, nullptr, 0, p); }
    k_gcn<1, 1><<<GN4, 256, 0, stream>>>((const unsigned int*)xW0b, ipM, csM, em, scal, dinv,
                                         gcn_b0 + r * 64, z0b, 64);
    { MG p{}; p.ost = 64; p.Wt[0] = G1j[r]; p.out[0] = xW1b;
      k_mgemm<64, 0, 1, 0, 0, 0, 1><<<GGM, 256, 0, stream>>>(z0b, 64, nullptr, 0, p); }
    k_gcn<0, 0><<<GN4, 256, 0, stream>>>((const unsigned int*)xW1b, ipM, csM, em, scal, dinv,
                                         gcn_b1 + r * 64, out_xtemp + r * 64, 192);
  }

  k_logits<<<GN4, 256, 0, stream>>>(out_xtemp, lin_W, lin_b, out_lsm);
}